// Round 10
// baseline (154.418 us; speedup 1.0000x reference)
//
#include <hip/hip_runtime.h>

#define EPSBN  1e-5f
#define NBLK_A 392           // convA: 50176 px / 128 per block; 392 = 8*49
#define NBLK_B 256           // convB: 64 img x 4 row-tiles (7 out rows each)

// ---------------- ws layout (bytes), total 61,701,888 (proven fit) ----------------
#define W1B_OFF 0u           // bf16 [192][9][96]   -> 331776
#define W2B_OFF 331776u      // bf16 [192][9][192]  -> 663552
#define WSB_OFF 995328u      // bf16 [192][128]     -> 49152 (ch 96..127 zero; row0 pad doubles as zbuf)
#define CS_OFF  1044480u     // 960 f32 -> 3840
#define XT_OFF  1048320u     // bf16 [64][56][56][96] -> 38535168 (unpadded NHWC)
#define ACT_OFF 39583488u    // bf16 [64][30][30][192] -> 22118400 (padded NHWC)

typedef __attribute__((ext_vector_type(8))) short bf16x8;
typedef __attribute__((ext_vector_type(4))) short bf16x4;
typedef __attribute__((ext_vector_type(4))) float f32x4;

__device__ __forceinline__ short f2bf(float f) {
    unsigned u = __float_as_uint(f);
    u += 0x7fffu + ((u >> 16) & 1u);
    return (short)(u >> 16);
}

// direct global->LDS, 16B per lane; LDS dest = wave-uniform base + lane*16; global src per-lane
__device__ __forceinline__ void gload16(const short* g, short* l) {
    __builtin_amdgcn_global_load_lds(
        (const __attribute__((address_space(1))) void*)g,
        (__attribute__((address_space(3))) void*)l, 16, 0, 0);
}

__device__ __forceinline__ float rational_eval(float v, const float* nm, const float* dn) {
    float p = nm[5];
    p = p * v + nm[4];
    p = p * v + nm[3];
    p = p * v + nm[2];
    p = p * v + nm[1];
    p = p * v + nm[0];
    float xa = fabsf(v);
    float q = 1.0f;
    float pw = xa;
    q += dn[0] * pw; pw *= xa;
    q += dn[1] * pw; pw *= xa;
    q += dn[2] * pw; pw *= xa;
    q += dn[3] * pw;
    float inv = __builtin_amdgcn_rcpf(q);
    inv = inv * (2.0f - q * inv);
    return p * inv;
}

__device__ __forceinline__ void sel_coeffs(int v, const float cnm[3][6], const float cdn[3][4],
                                           float nm[6], float dn[4]) {
#pragma unroll
    for (int i = 0; i < 6; i++) nm[i] = (v == 0) ? cnm[0][i] : ((v == 1) ? cnm[1][i] : cnm[2][i]);
#pragma unroll
    for (int i = 0; i < 4; i++) dn[i] = (v == 0) ? cdn[0][i] : ((v == 1) ? cdn[1][i] : cdn[2][i]);
}

// ---------------- prep kernels ----------------
extern "C" __global__ void prep_scales_kernel(
    const float* g1, const float* b1, const float* m1, const float* v1,
    const float* g2, const float* b2, const float* m2, const float* v2,
    const float* gs, const float* bs, const float* ms, const float* vs,
    float* cs)
{
    int i = threadIdx.x;
    if (i < 192) {
        float a1 = g1[i] * rsqrtf(v1[i] + EPSBN);
        float a2 = g2[i] * rsqrtf(v2[i] + EPSBN);
        float a3 = gs[i] * rsqrtf(vs[i] + EPSBN);
        cs[i]       = a1;
        cs[192 + i] = a2;
        cs[384 + i] = a3;
        cs[576 + i] = b1[i] - m1[i] * a1;                          // bias1
        cs[768 + i] = (b2[i] - m2[i] * a2) + (bs[i] - ms[i] * a3); // bias2 + biass
    }
}

// w [co][ci][kpos] (OIHW) -> wb [co][kpos][ci_dst], scaled by s[co]; ci >= CI_src zero-padded
extern "C" __global__ void prep_w_kernel(const float* __restrict__ w, const float* __restrict__ s,
                                         short* __restrict__ wb, int CI_src, int CI_dst, int KP, int total)
{
    int i = blockIdx.x * 256 + threadIdx.x;
    if (i >= total) return;
    int co = i / (CI_dst * KP);
    int r  = i - co * CI_dst * KP;
    int kpos = r / CI_dst;
    int ci = r - kpos * CI_dst;
    wb[i] = (ci < CI_src) ? f2bf(w[(co * CI_src + ci) * KP + kpos] * s[co]) : (short)0;
}

// zero the border ring of a [64][H][H][C] bf16 buffer
extern "C" __global__ void ring_zero_kernel(short* __restrict__ buf, int H, int C, int total)
{
    int ring = 2 * H + 2 * (H - 2);
    int i = blockIdx.x * 256 + threadIdx.x;
    if (i >= total) return;
    int c = i % C;
    int t = i / C;
    int rp = t % ring;
    int n = t / ring;
    int h, w;
    if (rp < H)           { h = 0;          w = rp; }
    else if (rp < 2 * H)  { h = H - 1;      w = rp - H; }
    else { int k = rp - 2 * H; h = (k >> 1) + 1; w = (k & 1) ? (H - 1) : 0; }
    buf[((n * H + h) * H + w) * C + c] = 0;
}

// x NCHW f32 [64][96][56][56] -> xt NHWC bf16 [64][56][56][96]
extern "C" __global__ __launch_bounds__(256)
void xpose_kernel(const float* __restrict__ x, short* __restrict__ xt)
{
    __shared__ float t[96 * 57];
    int b = blockIdx.x;
    int n = b / 56, h = b - n * 56;
    const float* src = x + n * (96 * 3136) + h * 56;
    for (int i = threadIdx.x; i < 96 * 28; i += 256) {
        int c = i / 28, w2 = i - c * 28;
        float2 v = *(const float2*)&src[c * 3136 + w2 * 2];
        t[c * 57 + w2 * 2]     = v.x;
        t[c * 57 + w2 * 2 + 1] = v.y;
    }
    __syncthreads();
    unsigned* dst = (unsigned*)(xt + (n * 56 + h) * 56 * 96);
    for (int i = threadIdx.x; i < 56 * 48; i += 256) {
        int w = i / 48, cp = i - (i / 48) * 48;
        unsigned lo = (unsigned short)f2bf(t[(2 * cp) * 57 + w]);
        unsigned hi = (unsigned short)f2bf(t[(2 * cp + 1) * 57 + w]);
        dst[w * 48 + cp] = lo | (hi << 16);
    }
}

// ---------------- kernel A: conv1(3x3 s2)+BN1+rational -> act (NHWC bf16, padded) ----------------
// (unchanged from round 9: 192co x 128px, 8 waves, BK=32)
extern "C" __global__ __launch_bounds__(512, 4)
void convA_kernel(const short* __restrict__ xt,
                  const short* __restrict__ w1b,
                  const short* __restrict__ zbuf,
                  const float* __restrict__ bias1,
                  const float* __restrict__ num_r, const float* __restrict__ den_r,
                  const float* __restrict__ num_g, const float* __restrict__ den_g,
                  const float* __restrict__ num_b, const float* __restrict__ den_b,
                  short* __restrict__ act)
{
    __shared__ short lA[2][192 * 32];
    __shared__ short lB[2][128 * 32];

    const int tid  = threadIdx.x;
    const int lane = tid & 63;
    const int wave = tid >> 6;
    const int wm = wave >> 1, wn = wave & 1;
    const int lbid = (blockIdx.x & 7) * 49 + (blockIdx.x >> 3);
    const int p0   = lbid * 128;

    const int sA = (((tid & 3) ^ ((tid >> 3) & 3))) * 8;
    const int r1 = tid >> 2;
    const int aw1a = r1 * 864 + sA;
    const int aw1b = (128 + r1) * 864 + sA;

    int xb0; bool top, left;
    {
        int p = p0 + r1;
        int n = p / 784; int pr = p - n * 784;
        int oh = pr / 28; int ow = pr - oh * 28;
        xb0 = ((n * 56 + 2 * oh) * 56 + 2 * ow) * 96 + sA;
        top = (oh == 0); left = (ow == 0);
    }

    const int l15 = lane & 15, ksl = lane >> 4;
    int ard[3], brd[4];
#pragma unroll
    for (int m = 0; m < 3; ++m) {
        int row = wm * 48 + m * 16 + l15;
        ard[m] = row * 32 + ((ksl ^ ((row >> 1) & 3)) << 3);
    }
#pragma unroll
    for (int n = 0; n < 4; ++n) {
        int row = wn * 64 + n * 16 + l15;
        brd[n] = row * 32 + ((ksl ^ ((row >> 1) & 3)) << 3);
    }

    auto stage = [&](int buf, int t) {
        int kpos = t / 3, cb = t - 3 * kpos;
        int kh = kpos / 3, kw = kpos - 3 * kh;
        gload16(&w1b[aw1a + t * 32], &lA[buf][wave * 512]);
        if (tid < 256) gload16(&w1b[aw1b + t * 32], &lA[buf][4096 + wave * 512]);
        int bko = ((kh - 1) * 56 + (kw - 1)) * 96 + cb * 32;
        const short* src = (((kh == 0) && top) || ((kw == 0) && left)) ? zbuf : &xt[xb0 + bko];
        gload16(src, &lB[buf][wave * 512]);
    };

    f32x4 acc[3][4];
#pragma unroll
    for (int m = 0; m < 3; m++)
#pragma unroll
        for (int n = 0; n < 4; n++) acc[m][n] = (f32x4){0.f, 0.f, 0.f, 0.f};

    stage(0, 0);
    int cur = 0;
    for (int t = 0; t < 27; ++t) {
        __syncthreads();
        if (t + 1 < 27) stage(cur ^ 1, t + 1);
        bf16x8 af[3];
#pragma unroll
        for (int m = 0; m < 3; ++m) af[m] = *(const bf16x8*)&lA[cur][ard[m]];
#pragma unroll
        for (int n = 0; n < 4; ++n) {
            bf16x8 bv = *(const bf16x8*)&lB[cur][brd[n]];
#pragma unroll
            for (int m = 0; m < 3; ++m)
                acc[m][n] = __builtin_amdgcn_mfma_f32_16x16x32_bf16(af[m], bv, acc[m][n], 0, 0, 0);
        }
        cur ^= 1;
    }

    float cnm[3][6], cdn[3][4];
#pragma unroll
    for (int i = 0; i < 6; i++) { cnm[0][i] = num_r[i]; cnm[1][i] = num_g[i]; cnm[2][i] = num_b[i]; }
#pragma unroll
    for (int i = 0; i < 4; i++) { cdn[0][i] = fabsf(den_r[i]); cdn[1][i] = fabsf(den_g[i]); cdn[2][i] = fabsf(den_b[i]); }

    int abase[4];
#pragma unroll
    for (int n = 0; n < 4; ++n) {
        int pp = p0 + wn * 64 + n * 16 + l15;
        int n2 = pp / 784; int r2 = pp - n2 * 784;
        int oh2 = r2 / 28; int ow2 = r2 - oh2 * 28;
        abase[n] = ((n2 * 30 + oh2 + 1) * 30 + ow2 + 1) * 192;
    }
#pragma unroll
    for (int m = 0; m < 3; ++m) {
        int cob = wm * 48 + m * 16 + (ksl << 2);
        float res[4][4];
#pragma unroll
        for (int r = 0; r < 4; ++r) {
            float nm[6], dn[4];
            sel_coeffs((cob + r) % 3, cnm, cdn, nm, dn);
            float bv = bias1[cob + r];
#pragma unroll
            for (int n = 0; n < 4; ++n)
                res[n][r] = rational_eval(acc[m][n][r] + bv, nm, dn);
        }
#pragma unroll
        for (int n = 0; n < 4; ++n) {
            bf16x4 pk;
#pragma unroll
            for (int r = 0; r < 4; ++r) pk[r] = f2bf(res[n][r]);
            *(bf16x4*)&act[abase[n] + cob] = pk;
        }
    }
}

// ---------------- kernel B (patch-resident): one image x 7 out rows (196 px, padded to 224).
// act patch (9x30x192, c&7-XOR swizzled) staged once; A double-buffered BK=32;
// shortcut via direct-global fragments in prologue (overlaps patch staging). ----------------
extern "C" __global__ __launch_bounds__(512, 2)
void convB_kernel(const short* __restrict__ act,
                  const short* __restrict__ xt,
                  const short* __restrict__ w2b,
                  const short* __restrict__ wsb,
                  const float* __restrict__ bias2s,
                  const float* __restrict__ num_r, const float* __restrict__ den_r,
                  const float* __restrict__ num_g, const float* __restrict__ den_g,
                  const float* __restrict__ num_b, const float* __restrict__ den_b,
                  float* __restrict__ outp)
{
    __shared__ short patch[53248];    // 104 KB (9*30*192 = 51840 used + slack)
    __shared__ short lA[2][6144];     // 12 KB each -> 128 KB total LDS

    const int tid  = threadIdx.x;
    const int lane = tid & 63;
    const int wave = tid >> 6;
    const int wm = wave >> 1, wn = wave & 1;        // 4 x 2 wave grid
    const int img = blockIdx.x >> 2;
    const int oh0 = (blockIdx.x & 3) * 7;

    const int l15 = lane & 15, ksl = lane >> 4;

    // ---- per-lane B-fragment tables (7 N-frags of 16 px each; px >= 196 are pad) ----
    int F0[7], F1[7], F2[7], C7[7], SCB[7], OB[7];
    bool VAL[7];
#pragma unroll
    for (int nf = 0; nf < 7; ++nf) {
        int p = wn * 112 + nf * 16 + l15;           // 0..223
        int orow = p / 28, ow = p - orow * 28;
        int r0 = orow;            if (r0 > 8) r0 = 8;
        int r1_ = orow + 1;       if (r1_ > 8) r1_ = 8;
        int r2_ = orow + 2;       if (r2_ > 8) r2_ = 8;
        F0[nf] = r0 * 5760 + ow * 192;
        F1[nf] = r1_ * 5760 + ow * 192;
        F2[nf] = r2_ * 5760 + ow * 192;
        C7[nf] = ow & 7;
        int ohc = oh0 + orow; if (ohc > 27) ohc = 27;
        SCB[nf] = ((img * 56 + 2 * ohc) * 56 + 2 * ow) * 96 + ksl * 8;
        OB[nf]  = img * (192 * 784) + (oh0 + orow) * 28 + ow;
        VAL[nf] = (p < 196);
    }
    // A read offsets (row>>1 XOR swizzle, matches staging)
    int ard[3], scA[3];
#pragma unroll
    for (int m = 0; m < 3; ++m) {
        int row = wm * 48 + m * 16 + l15;
        ard[m] = row * 32 + ((ksl ^ ((row >> 1) & 3)) << 3);
        scA[m] = row * 128 + ksl * 8;               // wsb row stride 128 (padded)
    }

    // ---- stage the act patch: 13 rounds, linear LDS dest, pre-swizzled global src ----
    const int prow0 = (img * 30 + oh0) * 30;        // padded act row base
#pragma unroll
    for (int j = 0; j < 13; ++j) {
        int o = (j * 512 + tid) * 8;
        if (o > 51832) o = 51832;                   // clamp tail chunks (dest = slack)
        int r = o / 5760;
        int rem = o - r * 5760;
        int c = rem / 192;
        int sl = (rem - c * 192) >> 3;
        const short* src = &act[(prow0 + r * 30 + c) * 192 + ((sl ^ (c & 7)) << 3)];
        gload16(src, &patch[(j * 512 + wave * 64) * 8]);
    }

    // ---- shortcut GEMM: direct-global fragments (latency hides under patch staging) ----
    f32x4 acc[3][7];
#pragma unroll
    for (int m = 0; m < 3; m++)
#pragma unroll
        for (int nf = 0; nf < 7; nf++) acc[m][nf] = (f32x4){0.f, 0.f, 0.f, 0.f};

#pragma unroll
    for (int s = 0; s < 3; ++s) {
        bf16x8 af[3], bfv[7];
#pragma unroll
        for (int m = 0; m < 3; ++m) af[m] = *(const bf16x8*)&wsb[scA[m] + s * 32];
#pragma unroll
        for (int nf = 0; nf < 7; ++nf) bfv[nf] = *(const bf16x8*)&xt[SCB[nf] + s * 32];
#pragma unroll
        for (int m = 0; m < 3; ++m)
#pragma unroll
            for (int nf = 0; nf < 7; ++nf)
                acc[m][nf] = __builtin_amdgcn_mfma_f32_16x16x32_bf16(af[m], bfv[nf], acc[m][nf], 0, 0, 0);
    }

    // ---- A staging (double-buffered, BK=32: 768 chunks -> 1.5 rounds) ----
    auto stageA = [&](int buf, int u) {
        int kpos = u / 6, cbk = u - 6 * kpos;
        int base = kpos * 192 + cbk * 32;
        {
            int row = tid >> 2, slot = tid & 3;
            gload16(&w2b[row * 1728 + base + ((slot ^ ((row >> 1) & 3)) << 3)],
                    &lA[buf][wave * 512]);
        }
        if (tid < 256) {
            int row = 128 + (tid >> 2), slot = tid & 3;
            gload16(&w2b[row * 1728 + base + ((slot ^ ((row >> 1) & 3)) << 3)],
                    &lA[buf][4096 + wave * 512]);
        }
    };

    stageA(0, 0);
    asm volatile("s_waitcnt vmcnt(0)" ::: "memory");
    __syncthreads();

    // ---- conv2 K-loop: 54 steps of BK=32 over the resident patch ----
    int cur = 0;
    for (int u = 0; u < 54; ++u) {
        if (u + 1 < 54) stageA(cur ^ 1, u + 1);
        int kpos = u / 6, cbk = u - 6 * kpos;
        int kh = kpos / 3, kw = kpos - 3 * kh;
        int kwo = kw * 192;
        int sg = cbk * 4 + ksl;
        bf16x8 af[3];
#pragma unroll
        for (int m = 0; m < 3; ++m) af[m] = *(const bf16x8*)&lA[cur][ard[m]];
#pragma unroll
        for (int nf = 0; nf < 7; ++nf) {
            int Fn = (kh == 0) ? F0[nf] : ((kh == 1) ? F1[nf] : F2[nf]);
            int addr = Fn + kwo + ((sg ^ ((C7[nf] + kw) & 7)) << 3);
            bf16x8 bv = *(const bf16x8*)&patch[addr];
#pragma unroll
            for (int m = 0; m < 3; ++m)
                acc[m][nf] = __builtin_amdgcn_mfma_f32_16x16x32_bf16(af[m], bv, acc[m][nf], 0, 0, 0);
        }
        __syncthreads();
        cur ^= 1;
    }

    // ---- epilogue: fused bias + rational -> out (NCHW f32), pad px masked ----
    float cnm[3][6], cdn[3][4];
#pragma unroll
    for (int i = 0; i < 6; i++) { cnm[0][i] = num_r[i]; cnm[1][i] = num_g[i]; cnm[2][i] = num_b[i]; }
#pragma unroll
    for (int i = 0; i < 4; i++) { cdn[0][i] = fabsf(den_r[i]); cdn[1][i] = fabsf(den_g[i]); cdn[2][i] = fabsf(den_b[i]); }

#pragma unroll
    for (int m = 0; m < 3; ++m) {
        int cob = wm * 48 + m * 16 + (ksl << 2);
#pragma unroll
        for (int r = 0; r < 4; ++r) {
            float nm[6], dn[4];
            sel_coeffs((cob + r) % 3, cnm, cdn, nm, dn);
            float bv = bias2s[cob + r];
#pragma unroll
            for (int nf = 0; nf < 7; ++nf) {
                if (VAL[nf])
                    outp[OB[nf] + (cob + r) * 784] = rational_eval(acc[m][nf][r] + bv, nm, dn);
            }
        }
    }
}

// ---------------- launcher ----------------
extern "C" void kernel_launch(void* const* d_in, const int* in_sizes, int n_in,
                              void* d_out, int out_size, void* d_ws, size_t ws_size,
                              hipStream_t stream)
{
    const float* x      = (const float*)d_in[0];
    const float* w1     = (const float*)d_in[1];
    const float* gamma1 = (const float*)d_in[2];
    const float* beta1  = (const float*)d_in[3];
    const float* mean1  = (const float*)d_in[4];
    const float* var1   = (const float*)d_in[5];
    const float* num_r  = (const float*)d_in[6];
    const float* den_r  = (const float*)d_in[7];
    const float* num_g  = (const float*)d_in[8];
    const float* den_g  = (const float*)d_in[9];
    const float* num_b  = (const float*)d_in[10];
    const float* den_b  = (const float*)d_in[11];
    const float* w2     = (const float*)d_in[12];
    const float* gamma2 = (const float*)d_in[13];
    const float* beta2  = (const float*)d_in[14];
    const float* var2   = (const float*)d_in[16];
    const float* mean2  = (const float*)d_in[15];
    const float* wsc    = (const float*)d_in[17];
    const float* gammas = (const float*)d_in[18];
    const float* betas  = (const float*)d_in[19];
    const float* means  = (const float*)d_in[20];
    const float* vars_  = (const float*)d_in[21];

    char* base = (char*)d_ws;
    short* w1b  = (short*)(base + W1B_OFF);
    short* w2b  = (short*)(base + W2B_OFF);
    short* wsb  = (short*)(base + WSB_OFF);
    float* cs   = (float*)(base + CS_OFF);
    short* xt   = (short*)(base + XT_OFF);
    short* act  = (short*)(base + ACT_OFF);
    float* outp = (float*)d_out;

    float* bias1  = cs + 576;
    float* bias2s = cs + 768;
    const short* zbuf = wsb + 96;   // row 0's zero-padded channels (64 B of zeros)

    prep_scales_kernel<<<1, 256, 0, stream>>>(gamma1, beta1, mean1, var1,
                                              gamma2, beta2, mean2, var2,
                                              gammas, betas, means, vars_, cs);

    prep_w_kernel<<<(192 * 96 * 9 + 255) / 256, 256, 0, stream>>>(w1, cs, w1b, 96, 96, 9, 192 * 96 * 9);
    prep_w_kernel<<<(192 * 192 * 9 + 255) / 256, 256, 0, stream>>>(w2, cs + 192, w2b, 192, 192, 9, 192 * 192 * 9);
    prep_w_kernel<<<(192 * 128 + 255) / 256, 256, 0, stream>>>(wsc, cs + 384, wsb, 96, 128, 1, 192 * 128);

    {
        int tot_a = 64 * (2 * 30 + 2 * 28) * 192;
        ring_zero_kernel<<<(tot_a + 255) / 256, 256, 0, stream>>>(act, 30, 192, tot_a);
    }

    xpose_kernel<<<64 * 56, 256, 0, stream>>>(x, xt);

    convA_kernel<<<NBLK_A, 512, 0, stream>>>(xt, w1b, zbuf, bias1,
                                             num_r, den_r, num_g, den_g, num_b, den_b,
                                             act);

    convB_kernel<<<NBLK_B, 512, 0, stream>>>(act, xt, w2b, wsb, bias2s,
                                             num_r, den_r, num_g, den_g, num_b, den_b,
                                             outp);
}

// Round 12
// 141.900 us; speedup vs baseline: 1.0882x; 1.0882x over previous
//
#include <hip/hip_runtime.h>

#define EPSBN  1e-5f
#define NBLK_A 392           // convA: 50176 px / 128 per block; 392 = 8*49
#define NBLK_B 256           // convB: 64 img x 4 row-tiles (7 out rows each)
#define PSTR   196           // patch per-pixel stride (shorts), 192 ch + 4 pad

// ---------------- ws layout (bytes), total 61,701,888 (proven fit) ----------------
#define W1B_OFF 0u           // bf16 [192][9][96]   -> 331776
#define W2B_OFF 331776u      // bf16 [192][9][192]  -> 663552
#define WSB_OFF 995328u      // bf16 [192][128]     -> 49152 (ch 96..127 zero; row0 pad doubles as zbuf)
#define CS_OFF  1044480u     // 960 f32 -> 3840
#define XT_OFF  1048320u     // bf16 [64][56][56][96] -> 38535168 (unpadded NHWC)
#define ACT_OFF 39583488u    // bf16 [64][30][30][192] -> 22118400 (padded NHWC)

typedef __attribute__((ext_vector_type(8))) short bf16x8;
typedef __attribute__((ext_vector_type(4))) short bf16x4;
typedef __attribute__((ext_vector_type(4))) float f32x4;

__device__ __forceinline__ short f2bf(float f) {
    unsigned u = __float_as_uint(f);
    u += 0x7fffu + ((u >> 16) & 1u);
    return (short)(u >> 16);
}

__device__ __forceinline__ void gload16(const short* g, short* l) {
    __builtin_amdgcn_global_load_lds(
        (const __attribute__((address_space(1))) void*)g,
        (__attribute__((address_space(3))) void*)l, 16, 0, 0);
}

__device__ __forceinline__ float rational_eval(float v, const float* nm, const float* dn) {
    float p = nm[5];
    p = p * v + nm[4];
    p = p * v + nm[3];
    p = p * v + nm[2];
    p = p * v + nm[1];
    p = p * v + nm[0];
    float xa = fabsf(v);
    float q = 1.0f;
    float pw = xa;
    q += dn[0] * pw; pw *= xa;
    q += dn[1] * pw; pw *= xa;
    q += dn[2] * pw; pw *= xa;
    q += dn[3] * pw;
    float inv = __builtin_amdgcn_rcpf(q);
    inv = inv * (2.0f - q * inv);
    return p * inv;
}

__device__ __forceinline__ void sel_coeffs(int v, const float cnm[3][6], const float cdn[3][4],
                                           float nm[6], float dn[4]) {
#pragma unroll
    for (int i = 0; i < 6; i++) nm[i] = (v == 0) ? cnm[0][i] : ((v == 1) ? cnm[1][i] : cnm[2][i]);
#pragma unroll
    for (int i = 0; i < 4; i++) dn[i] = (v == 0) ? cdn[0][i] : ((v == 1) ? cdn[1][i] : cdn[2][i]);
}

// ---------------- fused prep: w1/w2/ws bf16-repack (scale inline), act ring-zero, biases ----------------
// block ranges: [0,1296) w2 | [1296,1944) w1 | [1944,2040) ws | [2040,7608) ring | [7608] biases
extern "C" __global__ void prep_all_kernel(
    const float* __restrict__ w1, const float* __restrict__ w2, const float* __restrict__ wsc,
    const float* g1, const float* b1, const float* m1, const float* v1,
    const float* g2, const float* b2, const float* m2, const float* v2,
    const float* gs, const float* bs, const float* ms, const float* vs,
    short* __restrict__ w1b, short* __restrict__ w2b, short* __restrict__ wsb,
    float* __restrict__ cs, short* __restrict__ act)
{
    int blk = blockIdx.x;
    if (blk < 1296) {                               // w2 -> [co][kpos][192]
        int i = blk * 256 + threadIdx.x;            // < 331776 exactly
        int co = i / 1728;
        int r  = i - co * 1728;
        int kpos = r / 192;
        int ci = r - kpos * 192;
        float a = g2[co] * rsqrtf(v2[co] + EPSBN);
        w2b[i] = f2bf(w2[(co * 192 + ci) * 9 + kpos] * a);
    } else if (blk < 1944) {                        // w1 -> [co][kpos][96]
        int i = (blk - 1296) * 256 + threadIdx.x;   // < 165888 exactly
        int co = i / 864;
        int r  = i - co * 864;
        int kpos = r / 96;
        int ci = r - kpos * 96;
        float a = g1[co] * rsqrtf(v1[co] + EPSBN);
        w1b[i] = f2bf(w1[(co * 96 + ci) * 9 + kpos] * a);
    } else if (blk < 2040) {                        // ws -> [co][128], ci>=96 zero
        int i = (blk - 1944) * 256 + threadIdx.x;   // < 24576 exactly
        int co = i >> 7;
        int ci = i & 127;
        float a = gs[co] * rsqrtf(vs[co] + EPSBN);
        wsb[i] = (ci < 96) ? f2bf(wsc[co * 96 + ci] * a) : (short)0;
    } else if (blk < 7608) {                        // act pad-ring zero
        int i = (blk - 2040) * 256 + threadIdx.x;   // < 1425408 exactly
        int c = i % 192;
        int t = i / 192;
        int rp = t % 116;                           // ring positions for H=30
        int n = t / 116;
        int h, w;
        if (rp < 30)      { h = 0;  w = rp; }
        else if (rp < 60) { h = 29; w = rp - 30; }
        else { int k = rp - 60; h = (k >> 1) + 1; w = (k & 1) ? 29 : 0; }
        act[((n * 30 + h) * 30 + w) * 192 + c] = 0;
    } else {                                        // biases
        int i = threadIdx.x;
        if (i < 192) {
            float a1 = g1[i] * rsqrtf(v1[i] + EPSBN);
            float a2 = g2[i] * rsqrtf(v2[i] + EPSBN);
            float a3 = gs[i] * rsqrtf(vs[i] + EPSBN);
            cs[576 + i] = b1[i] - m1[i] * a1;
            cs[768 + i] = (b2[i] - m2[i] * a2) + (bs[i] - ms[i] * a3);
        }
    }
}

// x NCHW f32 [64][96][56][56] -> xt NHWC bf16 [64][56][56][96]
extern "C" __global__ __launch_bounds__(256)
void xpose_kernel(const float* __restrict__ x, short* __restrict__ xt)
{
    __shared__ float t[96 * 57];
    int b = blockIdx.x;
    int n = b / 56, h = b - n * 56;
    const float* src = x + n * (96 * 3136) + h * 56;
    for (int i = threadIdx.x; i < 96 * 28; i += 256) {
        int c = i / 28, w2 = i - c * 28;
        float2 v = *(const float2*)&src[c * 3136 + w2 * 2];
        t[c * 57 + w2 * 2]     = v.x;
        t[c * 57 + w2 * 2 + 1] = v.y;
    }
    __syncthreads();
    unsigned* dst = (unsigned*)(xt + (n * 56 + h) * 56 * 96);
    for (int i = threadIdx.x; i < 56 * 48; i += 256) {
        int w = i / 48, cp = i - (i / 48) * 48;
        unsigned lo = (unsigned short)f2bf(t[(2 * cp) * 57 + w]);
        unsigned hi = (unsigned short)f2bf(t[(2 * cp + 1) * 57 + w]);
        dst[w * 48 + cp] = lo | (hi << 16);
    }
}

// ---------------- kernel A: conv1(3x3 s2)+BN1+rational -> act (NHWC bf16, padded) ----------------
// (R9 verbatim: 192co x 128px, 8 waves, BK=32)
extern "C" __global__ __launch_bounds__(512, 4)
void convA_kernel(const short* __restrict__ xt,
                  const short* __restrict__ w1b,
                  const short* __restrict__ zbuf,
                  const float* __restrict__ bias1,
                  const float* __restrict__ num_r, const float* __restrict__ den_r,
                  const float* __restrict__ num_g, const float* __restrict__ den_g,
                  const float* __restrict__ num_b, const float* __restrict__ den_b,
                  short* __restrict__ act)
{
    __shared__ short lA[2][192 * 32];
    __shared__ short lB[2][128 * 32];

    const int tid  = threadIdx.x;
    const int lane = tid & 63;
    const int wave = tid >> 6;
    const int wm = wave >> 1, wn = wave & 1;
    const int lbid = (blockIdx.x & 7) * 49 + (blockIdx.x >> 3);
    const int p0   = lbid * 128;

    const int sA = (((tid & 3) ^ ((tid >> 3) & 3))) * 8;
    const int r1 = tid >> 2;
    const int aw1a = r1 * 864 + sA;
    const int aw1b = (128 + r1) * 864 + sA;

    int xb0; bool top, left;
    {
        int p = p0 + r1;
        int n = p / 784; int pr = p - n * 784;
        int oh = pr / 28; int ow = pr - oh * 28;
        xb0 = ((n * 56 + 2 * oh) * 56 + 2 * ow) * 96 + sA;
        top = (oh == 0); left = (ow == 0);
    }

    const int l15 = lane & 15, ksl = lane >> 4;
    int ard[3], brd[4];
#pragma unroll
    for (int m = 0; m < 3; ++m) {
        int row = wm * 48 + m * 16 + l15;
        ard[m] = row * 32 + ((ksl ^ ((row >> 1) & 3)) << 3);
    }
#pragma unroll
    for (int n = 0; n < 4; ++n) {
        int row = wn * 64 + n * 16 + l15;
        brd[n] = row * 32 + ((ksl ^ ((row >> 1) & 3)) << 3);
    }

    auto stage = [&](int buf, int t) {
        int kpos = t / 3, cb = t - 3 * kpos;
        int kh = kpos / 3, kw = kpos - 3 * kh;
        gload16(&w1b[aw1a + t * 32], &lA[buf][wave * 512]);
        if (tid < 256) gload16(&w1b[aw1b + t * 32], &lA[buf][4096 + wave * 512]);
        int bko = ((kh - 1) * 56 + (kw - 1)) * 96 + cb * 32;
        const short* src = (((kh == 0) && top) || ((kw == 0) && left)) ? zbuf : &xt[xb0 + bko];
        gload16(src, &lB[buf][wave * 512]);
    };

    f32x4 acc[3][4];
#pragma unroll
    for (int m = 0; m < 3; m++)
#pragma unroll
        for (int n = 0; n < 4; n++) acc[m][n] = (f32x4){0.f, 0.f, 0.f, 0.f};

    stage(0, 0);
    int cur = 0;
    for (int t = 0; t < 27; ++t) {
        __syncthreads();
        if (t + 1 < 27) stage(cur ^ 1, t + 1);
        bf16x8 af[3];
#pragma unroll
        for (int m = 0; m < 3; ++m) af[m] = *(const bf16x8*)&lA[cur][ard[m]];
#pragma unroll
        for (int n = 0; n < 4; ++n) {
            bf16x8 bv = *(const bf16x8*)&lB[cur][brd[n]];
#pragma unroll
            for (int m = 0; m < 3; ++m)
                acc[m][n] = __builtin_amdgcn_mfma_f32_16x16x32_bf16(af[m], bv, acc[m][n], 0, 0, 0);
        }
        cur ^= 1;
    }

    float cnm[3][6], cdn[3][4];
#pragma unroll
    for (int i = 0; i < 6; i++) { cnm[0][i] = num_r[i]; cnm[1][i] = num_g[i]; cnm[2][i] = num_b[i]; }
#pragma unroll
    for (int i = 0; i < 4; i++) { cdn[0][i] = fabsf(den_r[i]); cdn[1][i] = fabsf(den_g[i]); cdn[2][i] = fabsf(den_b[i]); }

    int abase[4];
#pragma unroll
    for (int n = 0; n < 4; ++n) {
        int pp = p0 + wn * 64 + n * 16 + l15;
        int n2 = pp / 784; int r2 = pp - n2 * 784;
        int oh2 = r2 / 28; int ow2 = r2 - oh2 * 28;
        abase[n] = ((n2 * 30 + oh2 + 1) * 30 + ow2 + 1) * 192;
    }
#pragma unroll
    for (int m = 0; m < 3; ++m) {
        int cob = wm * 48 + m * 16 + (ksl << 2);
        float res[4][4];
#pragma unroll
        for (int r = 0; r < 4; ++r) {
            float nm[6], dn[4];
            sel_coeffs((cob + r) % 3, cnm, cdn, nm, dn);
            float bv = bias1[cob + r];
#pragma unroll
            for (int n = 0; n < 4; ++n)
                res[n][r] = rational_eval(acc[m][n][r] + bv, nm, dn);
        }
#pragma unroll
        for (int n = 0; n < 4; ++n) {
            bf16x4 pk;
#pragma unroll
            for (int r = 0; r < 4; ++r) pk[r] = f2bf(res[n][r]);
            *(bf16x4*)&act[abase[n] + cob] = pk;
        }
    }
}

// ---------------- kernel B (patch-resident v2, staging-count FIXED): one image x 7 out rows.
// Pad-stride patch (196 ch/px) via reg-staging (24 chunks/px); FULL-UNROLL K-loop;
// A double-buffered BK=32, waves 0-5 stage uniformly, issue-early. ----------------
extern "C" __global__ __launch_bounds__(512, 1)
void convB_kernel(const short* __restrict__ act,
                  const short* __restrict__ xt,
                  const short* __restrict__ w2b,
                  const short* __restrict__ wsb,
                  const float* __restrict__ bias2s,
                  const float* __restrict__ num_r, const float* __restrict__ den_r,
                  const float* __restrict__ num_g, const float* __restrict__ den_g,
                  const float* __restrict__ num_b, const float* __restrict__ den_b,
                  float* __restrict__ outp)
{
    __shared__ short patch[9 * 30 * PSTR];   // 105,840 B
    __shared__ short lA[2][192 * 32];        // 12,288 B each -> 130,416 B total

    const int tid  = threadIdx.x;
    const int lane = tid & 63;
    const int wave = tid >> 6;
    const int wm = wave >> 1, wn = wave & 1;        // 4 x 2 wave grid
    const int img = blockIdx.x >> 2;
    const int oh0 = (blockIdx.x & 3) * 7;

    const int l15 = lane & 15, ksl = lane >> 4;

    // per-lane B-fragment tables (7 N-frags of 16 px; px >= 196 are pad, clamped+masked)
    int PB[7], SCB[7], OB[7];
    bool VAL[7];
#pragma unroll
    for (int nf = 0; nf < 7; ++nf) {
        int p = wn * 112 + nf * 16 + l15;           // 0..223
        int orow = p / 28, ow = p - orow * 28;
        int orc = orow > 6 ? 6 : orow;
        PB[nf] = (orc * 30 + ow) * PSTR + ksl * 8;
        int ohc = oh0 + orc;
        SCB[nf] = ((img * 56 + 2 * ohc) * 56 + 2 * ow) * 96 + ksl * 8;
        OB[nf]  = img * (192 * 784) + (oh0 + orow) * 28 + ow;
        VAL[nf] = (p < 196);
    }
    // A read offsets (slot-XOR swizzle, matches staging)
    int ard[3], scA[3];
#pragma unroll
    for (int m = 0; m < 3; ++m) {
        int row = wm * 48 + m * 16 + l15;
        ard[m] = row * 32 + ((ksl ^ ((row >> 1) & 3)) << 3);
        scA[m] = row * 128 + ksl * 8;               // wsb row stride 128 (padded)
    }

    // ---- patch reg-staging: 6480 16B chunks (270 px x 24 slots of 8 ch) ----
    const int prow0 = (img * 30 + oh0) * 30;
#pragma unroll
    for (int t = 0; t < 13; ++t) {
        int idx = t * 512 + tid;
        if (idx < 6480) {
            int pix = idx / 24, sl = idx - pix * 24;
            bf16x8 v = *(const bf16x8*)&act[(prow0 + (pix / 30) * 30 + (pix % 30)) * 192 + sl * 8];
            *(bf16x8*)&patch[pix * PSTR + sl * 8] = v;
        }
    }

    // ---- shortcut GEMM: direct-global fragments (overlaps patch stores in flight) ----
    f32x4 acc[3][7];
#pragma unroll
    for (int m = 0; m < 3; m++)
#pragma unroll
        for (int nf = 0; nf < 7; nf++) acc[m][nf] = (f32x4){0.f, 0.f, 0.f, 0.f};

#pragma unroll
    for (int s = 0; s < 3; ++s) {
        bf16x8 af[3], bfv[7];
#pragma unroll
        for (int m = 0; m < 3; ++m) af[m] = *(const bf16x8*)&wsb[scA[m] + s * 32];
#pragma unroll
        for (int nf = 0; nf < 7; ++nf) bfv[nf] = *(const bf16x8*)&xt[SCB[nf] + s * 32];
#pragma unroll
        for (int m = 0; m < 3; ++m)
#pragma unroll
            for (int nf = 0; nf < 7; ++nf)
                acc[m][nf] = __builtin_amdgcn_mfma_f32_16x16x32_bf16(af[m], bfv[nf], acc[m][nf], 0, 0, 0);
    }

    // ---- A staging: waves 0..5 stage 2 chunks/step each (uniform); linear LDS dest ----
    auto stageA = [&](int buf, int kw_off) {
        if (wave < 6) {
#pragma unroll
            for (int j = 0; j < 2; ++j) {
                int rg = wave * 2 + j;                    // 0..11 (1KB region)
                int row = rg * 16 + (lane >> 2);          // 0..191
                int sl = (lane & 3) ^ ((row >> 1) & 3);   // pre-swizzled source slot
                gload16(&w2b[row * 1728 + kw_off + sl * 8], &lA[buf][rg * 512]);
            }
        }
    };

    stageA(0, 0);
    __syncthreads();     // drains patch stores + first A stage + sc loads

    // ---- conv2 K-loop: 54 fully-unrolled BK=32 steps over the resident patch ----
#pragma unroll
    for (int u = 0; u < 54; ++u) {
        const int cur = u & 1;
        if (u + 1 < 54) {
            const int un = u + 1, kp = un / 6, cb = un - 6 * kp;
            stageA(cur ^ 1, kp * 192 + cb * 32);
        }
        const int kpos = u / 6, cbk = u - 6 * kpos;
        const int kh = kpos / 3, kw = kpos - 3 * kh;
        const int KOFF = (kh * 30 + kw) * PSTR + cbk * 32;   // compile-time imm
        bf16x8 af[3];
#pragma unroll
        for (int m = 0; m < 3; ++m) af[m] = *(const bf16x8*)&lA[cur][ard[m]];
#pragma unroll
        for (int nf = 0; nf < 7; ++nf) {
            bf16x8 bv = *(const bf16x8*)&patch[PB[nf] + KOFF];
#pragma unroll
            for (int m = 0; m < 3; ++m)
                acc[m][nf] = __builtin_amdgcn_mfma_f32_16x16x32_bf16(af[m], bv, acc[m][nf], 0, 0, 0);
        }
        __syncthreads();
    }

    // ---- epilogue: fused bias + rational -> out (NCHW f32), pad px masked ----
    float cnm[3][6], cdn[3][4];
#pragma unroll
    for (int i = 0; i < 6; i++) { cnm[0][i] = num_r[i]; cnm[1][i] = num_g[i]; cnm[2][i] = num_b[i]; }
#pragma unroll
    for (int i = 0; i < 4; i++) { cdn[0][i] = fabsf(den_r[i]); cdn[1][i] = fabsf(den_g[i]); cdn[2][i] = fabsf(den_b[i]); }

#pragma unroll
    for (int m = 0; m < 3; ++m) {
        int cob = wm * 48 + m * 16 + (ksl << 2);
#pragma unroll
        for (int r = 0; r < 4; ++r) {
            float nm[6], dn[4];
            sel_coeffs((cob + r) % 3, cnm, cdn, nm, dn);
            float bv = bias2s[cob + r];
#pragma unroll
            for (int nf = 0; nf < 7; ++nf) {
                if (VAL[nf])
                    outp[OB[nf] + (cob + r) * 784] = rational_eval(acc[m][nf][r] + bv, nm, dn);
            }
        }
    }
}

// ---------------- launcher ----------------
extern "C" void kernel_launch(void* const* d_in, const int* in_sizes, int n_in,
                              void* d_out, int out_size, void* d_ws, size_t ws_size,
                              hipStream_t stream)
{
    const float* x      = (const float*)d_in[0];
    const float* w1     = (const float*)d_in[1];
    const float* gamma1 = (const float*)d_in[2];
    const float* beta1  = (const float*)d_in[3];
    const float* mean1  = (const float*)d_in[4];
    const float* var1   = (const float*)d_in[5];
    const float* num_r  = (const float*)d_in[6];
    const float* den_r  = (const float*)d_in[7];
    const float* num_g  = (const float*)d_in[8];
    const float* den_g  = (const float*)d_in[9];
    const float* num_b  = (const float*)d_in[10];
    const float* den_b  = (const float*)d_in[11];
    const float* w2     = (const float*)d_in[12];
    const float* gamma2 = (const float*)d_in[13];
    const float* beta2  = (const float*)d_in[14];
    const float* mean2  = (const float*)d_in[15];
    const float* var2   = (const float*)d_in[16];
    const float* wsc    = (const float*)d_in[17];
    const float* gammas = (const float*)d_in[18];
    const float* betas  = (const float*)d_in[19];
    const float* means  = (const float*)d_in[20];
    const float* vars_  = (const float*)d_in[21];

    char* base = (char*)d_ws;
    short* w1b  = (short*)(base + W1B_OFF);
    short* w2b  = (short*)(base + W2B_OFF);
    short* wsb  = (short*)(base + WSB_OFF);
    float* cs   = (float*)(base + CS_OFF);
    short* xt   = (short*)(base + XT_OFF);
    short* act  = (short*)(base + ACT_OFF);
    float* outp = (float*)d_out;

    float* bias1  = cs + 576;
    float* bias2s = cs + 768;
    const short* zbuf = wsb + 96;   // row 0's zero-padded channels (64 B of zeros)

    prep_all_kernel<<<7609, 256, 0, stream>>>(w1, w2, wsc,
                                              gamma1, beta1, mean1, var1,
                                              gamma2, beta2, mean2, var2,
                                              gammas, betas, means, vars_,
                                              w1b, w2b, wsb, cs, act);

    xpose_kernel<<<64 * 56, 256, 0, stream>>>(x, xt);

    convA_kernel<<<NBLK_A, 512, 0, stream>>>(xt, w1b, zbuf, bias1,
                                             num_r, den_r, num_g, den_g, num_b, den_b,
                                             act);

    convB_kernel<<<NBLK_B, 512, 0, stream>>>(act, xt, w2b, wsb, bias2s,
                                             num_r, den_r, num_g, den_g, num_b, den_b,
                                             outp);
}

// Round 13
// 139.779 us; speedup vs baseline: 1.1047x; 1.0152x over previous
//
#include <hip/hip_runtime.h>

#define EPSBN  1e-5f
#define NBLK_A 392           // convA: 50176 px / 128 per block; 392 = 8*49
#define NBLK_B 256           // convB: 64 img x 4 row-tiles (7 out rows each)
#define PSTR   196           // patch per-pixel stride (shorts), 192 ch + 4 pad

// ---------------- ws layout (bytes), total 61,701,888 (proven fit) ----------------
#define W1B_OFF 0u           // bf16 [192][9][96]   -> 331776
#define W2B_OFF 331776u      // bf16 [192][9][192]  -> 663552
#define WSB_OFF 995328u      // bf16 [192][128]     -> 49152 (ch 96..127 zero; row0 pad doubles as zbuf)
#define CS_OFF  1044480u     // 960 f32 -> 3840
#define XT_OFF  1048320u     // bf16 [64][56][56][96] -> 38535168 (unpadded NHWC)
#define ACT_OFF 39583488u    // bf16 [64][30][30][192] -> 22118400 (padded NHWC)

typedef __attribute__((ext_vector_type(8))) short bf16x8;
typedef __attribute__((ext_vector_type(4))) short bf16x4;
typedef __attribute__((ext_vector_type(4))) float f32x4;

#define WAITV(N) asm volatile("s_waitcnt vmcnt(" #N ")" ::: "memory")

__device__ __forceinline__ short f2bf(float f) {
    unsigned u = __float_as_uint(f);
    u += 0x7fffu + ((u >> 16) & 1u);
    return (short)(u >> 16);
}

__device__ __forceinline__ void gload16(const short* g, short* l) {
    __builtin_amdgcn_global_load_lds(
        (const __attribute__((address_space(1))) void*)g,
        (__attribute__((address_space(3))) void*)l, 16, 0, 0);
}

__device__ __forceinline__ float rational_eval(float v, const float* nm, const float* dn) {
    float p = nm[5];
    p = p * v + nm[4];
    p = p * v + nm[3];
    p = p * v + nm[2];
    p = p * v + nm[1];
    p = p * v + nm[0];
    float xa = fabsf(v);
    float q = 1.0f;
    float pw = xa;
    q += dn[0] * pw; pw *= xa;
    q += dn[1] * pw; pw *= xa;
    q += dn[2] * pw; pw *= xa;
    q += dn[3] * pw;
    float inv = __builtin_amdgcn_rcpf(q);
    inv = inv * (2.0f - q * inv);
    return p * inv;
}

__device__ __forceinline__ void sel_coeffs(int v, const float cnm[3][6], const float cdn[3][4],
                                           float nm[6], float dn[4]) {
#pragma unroll
    for (int i = 0; i < 6; i++) nm[i] = (v == 0) ? cnm[0][i] : ((v == 1) ? cnm[1][i] : cnm[2][i]);
#pragma unroll
    for (int i = 0; i < 4; i++) dn[i] = (v == 0) ? cdn[0][i] : ((v == 1) ? cdn[1][i] : cdn[2][i]);
}

// ---------------- fused prep: w1/w2/ws bf16-repack (scale inline), act ring-zero, biases ----------------
extern "C" __global__ void prep_all_kernel(
    const float* __restrict__ w1, const float* __restrict__ w2, const float* __restrict__ wsc,
    const float* g1, const float* b1, const float* m1, const float* v1,
    const float* g2, const float* b2, const float* m2, const float* v2,
    const float* gs, const float* bs, const float* ms, const float* vs,
    short* __restrict__ w1b, short* __restrict__ w2b, short* __restrict__ wsb,
    float* __restrict__ cs, short* __restrict__ act)
{
    int blk = blockIdx.x;
    if (blk < 1296) {                               // w2 -> [co][kpos][192]
        int i = blk * 256 + threadIdx.x;
        int co = i / 1728;
        int r  = i - co * 1728;
        int kpos = r / 192;
        int ci = r - kpos * 192;
        float a = g2[co] * rsqrtf(v2[co] + EPSBN);
        w2b[i] = f2bf(w2[(co * 192 + ci) * 9 + kpos] * a);
    } else if (blk < 1944) {                        // w1 -> [co][kpos][96]
        int i = (blk - 1296) * 256 + threadIdx.x;
        int co = i / 864;
        int r  = i - co * 864;
        int kpos = r / 96;
        int ci = r - kpos * 96;
        float a = g1[co] * rsqrtf(v1[co] + EPSBN);
        w1b[i] = f2bf(w1[(co * 96 + ci) * 9 + kpos] * a);
    } else if (blk < 2040) {                        // ws -> [co][128], ci>=96 zero
        int i = (blk - 1944) * 256 + threadIdx.x;
        int co = i >> 7;
        int ci = i & 127;
        float a = gs[co] * rsqrtf(vs[co] + EPSBN);
        wsb[i] = (ci < 96) ? f2bf(wsc[co * 96 + ci] * a) : (short)0;
    } else if (blk < 7608) {                        // act pad-ring zero
        int i = (blk - 2040) * 256 + threadIdx.x;
        int c = i % 192;
        int t = i / 192;
        int rp = t % 116;
        int n = t / 116;
        int h, w;
        if (rp < 30)      { h = 0;  w = rp; }
        else if (rp < 60) { h = 29; w = rp - 30; }
        else { int k = rp - 60; h = (k >> 1) + 1; w = (k & 1) ? 29 : 0; }
        act[((n * 30 + h) * 30 + w) * 192 + c] = 0;
    } else {                                        // biases
        int i = threadIdx.x;
        if (i < 192) {
            float a1 = g1[i] * rsqrtf(v1[i] + EPSBN);
            float a2 = g2[i] * rsqrtf(v2[i] + EPSBN);
            float a3 = gs[i] * rsqrtf(vs[i] + EPSBN);
            cs[576 + i] = b1[i] - m1[i] * a1;
            cs[768 + i] = (b2[i] - m2[i] * a2) + (bs[i] - ms[i] * a3);
        }
    }
}

// x NCHW f32 [64][96][56][56] -> xt NHWC bf16 [64][56][56][96]
extern "C" __global__ __launch_bounds__(256)
void xpose_kernel(const float* __restrict__ x, short* __restrict__ xt)
{
    __shared__ float t[96 * 57];
    int b = blockIdx.x;
    int n = b / 56, h = b - n * 56;
    const float* src = x + n * (96 * 3136) + h * 56;
    for (int i = threadIdx.x; i < 96 * 28; i += 256) {
        int c = i / 28, w2 = i - c * 28;
        float2 v = *(const float2*)&src[c * 3136 + w2 * 2];
        t[c * 57 + w2 * 2]     = v.x;
        t[c * 57 + w2 * 2 + 1] = v.y;
    }
    __syncthreads();
    unsigned* dst = (unsigned*)(xt + (n * 56 + h) * 56 * 96);
    for (int i = threadIdx.x; i < 56 * 48; i += 256) {
        int w = i / 48, cp = i - (i / 48) * 48;
        unsigned lo = (unsigned short)f2bf(t[(2 * cp) * 57 + w]);
        unsigned hi = (unsigned short)f2bf(t[(2 * cp + 1) * 57 + w]);
        dst[w * 48 + cp] = lo | (hi << 16);
    }
}

// ---------------- kernel A: conv1(3x3 s2)+BN1+rational -> act (NHWC bf16, padded) ----------------
// 192co x 128px, 8 waves, BK=32; 3-buffer + counted vmcnt + raw barrier, full unroll.
extern "C" __global__ __launch_bounds__(512, 4)
void convA_kernel(const short* __restrict__ xt,
                  const short* __restrict__ w1b,
                  const short* __restrict__ zbuf,
                  const float* __restrict__ bias1,
                  const float* __restrict__ num_r, const float* __restrict__ den_r,
                  const float* __restrict__ num_g, const float* __restrict__ den_g,
                  const float* __restrict__ num_b, const float* __restrict__ den_b,
                  short* __restrict__ act)
{
    __shared__ short lA[3][192 * 32];   // 36,864 B
    __shared__ short lB[3][128 * 32];   // 24,576 B -> 61,440 total

    const int tid  = threadIdx.x;
    const int lane = tid & 63;
    const int wave = tid >> 6;
    const int wm = wave >> 1, wn = wave & 1;
    const int lbid = (blockIdx.x & 7) * 49 + (blockIdx.x >> 3);
    const int p0   = lbid * 128;

    const int sA = (((tid & 3) ^ ((tid >> 3) & 3))) * 8;
    const int r1 = tid >> 2;
    const int aw1a = r1 * 864 + sA;
    const int aw1b = (128 + r1) * 864 + sA;

    int xb0; bool top, left;
    {
        int p = p0 + r1;
        int n = p / 784; int pr = p - n * 784;
        int oh = pr / 28; int ow = pr - oh * 28;
        xb0 = ((n * 56 + 2 * oh) * 56 + 2 * ow) * 96 + sA;
        top = (oh == 0); left = (ow == 0);
    }

    const int l15 = lane & 15, ksl = lane >> 4;
    int ard[3], brd[4];
#pragma unroll
    for (int m = 0; m < 3; ++m) {
        int row = wm * 48 + m * 16 + l15;
        ard[m] = row * 32 + ((ksl ^ ((row >> 1) & 3)) << 3);
    }
#pragma unroll
    for (int n = 0; n < 4; ++n) {
        int row = wn * 64 + n * 16 + l15;
        brd[n] = row * 32 + ((ksl ^ ((row >> 1) & 3)) << 3);
    }

    auto stage = [&](int buf, int t) {
        int kpos = t / 3, cb = t - 3 * kpos;
        int kh = kpos / 3, kw = kpos - 3 * kh;
        gload16(&w1b[aw1a + t * 32], &lA[buf][wave * 512]);
        if (tid < 256) gload16(&w1b[aw1b + t * 32], &lA[buf][4096 + wave * 512]);
        int bko = ((kh - 1) * 56 + (kw - 1)) * 96 + cb * 32;
        const short* src = (((kh == 0) && top) || ((kw == 0) && left)) ? zbuf : &xt[xb0 + bko];
        gload16(src, &lB[buf][wave * 512]);
    };

    f32x4 acc[3][4];
#pragma unroll
    for (int m = 0; m < 3; m++)
#pragma unroll
        for (int n = 0; n < 4; n++) acc[m][n] = (f32x4){0.f, 0.f, 0.f, 0.f};

    stage(0, 0);
    stage(1, 1);
    WAITV(0);
    __builtin_amdgcn_s_barrier();

#pragma unroll
    for (int t = 0; t < 27; ++t) {
        const int cur = t % 3;
        if (t + 2 < 27) stage((t + 2) % 3, t + 2);
        bf16x8 af[3];
#pragma unroll
        for (int m = 0; m < 3; ++m) af[m] = *(const bf16x8*)&lA[cur][ard[m]];
#pragma unroll
        for (int n = 0; n < 4; ++n) {
            bf16x8 bv = *(const bf16x8*)&lB[cur][brd[n]];
#pragma unroll
            for (int m = 0; m < 3; ++m)
                acc[m][n] = __builtin_amdgcn_mfma_f32_16x16x32_bf16(af[m], bv, acc[m][n], 0, 0, 0);
        }
        if (t + 1 < 27) {
            if (t + 2 < 27) {
                if (wave < 4) { WAITV(3); } else { WAITV(2); }
            } else {
                WAITV(0);
            }
            __builtin_amdgcn_s_barrier();
        }
    }

    float cnm[3][6], cdn[3][4];
#pragma unroll
    for (int i = 0; i < 6; i++) { cnm[0][i] = num_r[i]; cnm[1][i] = num_g[i]; cnm[2][i] = num_b[i]; }
#pragma unroll
    for (int i = 0; i < 4; i++) { cdn[0][i] = fabsf(den_r[i]); cdn[1][i] = fabsf(den_g[i]); cdn[2][i] = fabsf(den_b[i]); }

    int abase[4];
#pragma unroll
    for (int n = 0; n < 4; ++n) {
        int pp = p0 + wn * 64 + n * 16 + l15;
        int n2 = pp / 784; int r2 = pp - n2 * 784;
        int oh2 = r2 / 28; int ow2 = r2 - oh2 * 28;
        abase[n] = ((n2 * 30 + oh2 + 1) * 30 + ow2 + 1) * 192;
    }
#pragma unroll
    for (int m = 0; m < 3; ++m) {
        int cob = wm * 48 + m * 16 + (ksl << 2);
        float res[4][4];
#pragma unroll
        for (int r = 0; r < 4; ++r) {
            float nm[6], dn[4];
            sel_coeffs((cob + r) % 3, cnm, cdn, nm, dn);
            float bv = bias1[cob + r];
#pragma unroll
            for (int n = 0; n < 4; ++n)
                res[n][r] = rational_eval(acc[m][n][r] + bv, nm, dn);
        }
#pragma unroll
        for (int n = 0; n < 4; ++n) {
            bf16x4 pk;
#pragma unroll
            for (int r = 0; r < 4; ++r) pk[r] = f2bf(res[n][r]);
            *(bf16x4*)&act[abase[n] + cob] = pk;
        }
    }
}

// ---------------- kernel B (patch-resident v3): one image x 7 out rows.
// Patch staged once (reg-staging); A 3-buffer gload_lds with counted vmcnt + raw barrier;
// FULL-UNROLL K-loop -> imm-offset ds_reads. ----------------
extern "C" __global__ __launch_bounds__(512, 1)
void convB_kernel(const short* __restrict__ act,
                  const short* __restrict__ xt,
                  const short* __restrict__ w2b,
                  const short* __restrict__ wsb,
                  const float* __restrict__ bias2s,
                  const float* __restrict__ num_r, const float* __restrict__ den_r,
                  const float* __restrict__ num_g, const float* __restrict__ den_g,
                  const float* __restrict__ num_b, const float* __restrict__ den_b,
                  float* __restrict__ outp)
{
    __shared__ short patch[9 * 30 * PSTR];   // 105,840 B
    __shared__ short lA[3][192 * 32];        // 36,864 B -> 142,704 B total

    const int tid  = threadIdx.x;
    const int lane = tid & 63;
    const int wave = tid >> 6;
    const int wm = wave >> 1, wn = wave & 1;        // 4 x 2 wave grid
    const int img = blockIdx.x >> 2;
    const int oh0 = (blockIdx.x & 3) * 7;

    const int l15 = lane & 15, ksl = lane >> 4;

    // per-lane B-fragment tables (7 N-frags of 16 px; px >= 196 are pad, clamped+masked)
    int PB[7], SCB[7], OB[7];
    bool VAL[7];
#pragma unroll
    for (int nf = 0; nf < 7; ++nf) {
        int p = wn * 112 + nf * 16 + l15;           // 0..223
        int orow = p / 28, ow = p - orow * 28;
        int orc = orow > 6 ? 6 : orow;
        PB[nf] = (orc * 30 + ow) * PSTR + ksl * 8;
        int ohc = oh0 + orc;
        SCB[nf] = ((img * 56 + 2 * ohc) * 56 + 2 * ow) * 96 + ksl * 8;
        OB[nf]  = img * (192 * 784) + (oh0 + orow) * 28 + ow;
        VAL[nf] = (p < 196);
    }
    int ard[3], scA[3];
#pragma unroll
    for (int m = 0; m < 3; ++m) {
        int row = wm * 48 + m * 16 + l15;
        ard[m] = row * 32 + ((ksl ^ ((row >> 1) & 3)) << 3);
        scA[m] = row * 128 + ksl * 8;               // wsb row stride 128 (padded)
    }

    // ---- patch reg-staging: 6480 16B chunks (270 px x 24 slots of 8 ch) ----
    const int prow0 = (img * 30 + oh0) * 30;
#pragma unroll
    for (int t = 0; t < 13; ++t) {
        int idx = t * 512 + tid;
        if (idx < 6480) {
            int pix = idx / 24, sl = idx - pix * 24;
            bf16x8 v = *(const bf16x8*)&act[(prow0 + (pix / 30) * 30 + (pix % 30)) * 192 + sl * 8];
            *(bf16x8*)&patch[pix * PSTR + sl * 8] = v;
        }
    }

    // ---- shortcut GEMM: direct-global fragments (overlaps patch staging) ----
    f32x4 acc[3][7];
#pragma unroll
    for (int m = 0; m < 3; m++)
#pragma unroll
        for (int nf = 0; nf < 7; nf++) acc[m][nf] = (f32x4){0.f, 0.f, 0.f, 0.f};

#pragma unroll
    for (int s = 0; s < 3; ++s) {
        bf16x8 af[3], bfv[7];
#pragma unroll
        for (int m = 0; m < 3; ++m) af[m] = *(const bf16x8*)&wsb[scA[m] + s * 32];
#pragma unroll
        for (int nf = 0; nf < 7; ++nf) bfv[nf] = *(const bf16x8*)&xt[SCB[nf] + s * 32];
#pragma unroll
        for (int m = 0; m < 3; ++m)
#pragma unroll
            for (int nf = 0; nf < 7; ++nf)
                acc[m][nf] = __builtin_amdgcn_mfma_f32_16x16x32_bf16(af[m], bfv[nf], acc[m][nf], 0, 0, 0);
    }

    // ---- A staging: waves 0..5 stage 2 chunks/step each; linear LDS dest ----
    auto stageA = [&](int buf, int kw_off) {
        if (wave < 6) {
#pragma unroll
            for (int j = 0; j < 2; ++j) {
                int rg = wave * 2 + j;                    // 0..11 (1KB region)
                int row = rg * 16 + (lane >> 2);          // 0..191
                int sl = (lane & 3) ^ ((row >> 1) & 3);   // pre-swizzled source slot
                gload16(&w2b[row * 1728 + kw_off + sl * 8], &lA[buf][rg * 512]);
            }
        }
    };

    stageA(0, 0);
    stageA(1, 192 + 0 * 32 - 160);   // step 1: kp=0, cb=1 -> offset 32
    // (literal form below keeps intent clear)
    // step 1 offset = 32; the expression above equals 32.
    __syncthreads();   // drains patch writes + sc loads + stageA(0),(1)

    // ---- conv2 K-loop: 54 fully-unrolled BK=32 steps; counted vmcnt + raw barrier ----
#pragma unroll
    for (int u = 0; u < 54; ++u) {
        const int cur = u % 3;
        if (u + 2 < 54) {
            const int un = u + 2, kp = un / 6, cb = un - 6 * kp;
            stageA((u + 2) % 3, kp * 192 + cb * 32);
        }
        const int kpos = u / 6, cbk = u - 6 * kpos;
        const int kh = kpos / 3, kw = kpos - 3 * kh;
        const int KOFF = (kh * 30 + kw) * PSTR + cbk * 32;   // compile-time imm
        bf16x8 af[3];
#pragma unroll
        for (int m = 0; m < 3; ++m) af[m] = *(const bf16x8*)&lA[cur][ard[m]];
#pragma unroll
        for (int nf = 0; nf < 7; ++nf) {
            bf16x8 bv = *(const bf16x8*)&patch[PB[nf] + KOFF];
#pragma unroll
            for (int m = 0; m < 3; ++m)
                acc[m][nf] = __builtin_amdgcn_mfma_f32_16x16x32_bf16(af[m], bv, acc[m][nf], 0, 0, 0);
        }
        if (u + 1 < 54) {
            if (u + 2 < 54) { WAITV(2); } else { WAITV(0); }
            __builtin_amdgcn_s_barrier();
        }
    }

    // ---- epilogue: fused bias + rational -> out (NCHW f32), pad px masked ----
    float cnm[3][6], cdn[3][4];
#pragma unroll
    for (int i = 0; i < 6; i++) { cnm[0][i] = num_r[i]; cnm[1][i] = num_g[i]; cnm[2][i] = num_b[i]; }
#pragma unroll
    for (int i = 0; i < 4; i++) { cdn[0][i] = fabsf(den_r[i]); cdn[1][i] = fabsf(den_g[i]); cdn[2][i] = fabsf(den_b[i]); }

#pragma unroll
    for (int m = 0; m < 3; ++m) {
        int cob = wm * 48 + m * 16 + (ksl << 2);
#pragma unroll
        for (int r = 0; r < 4; ++r) {
            float nm[6], dn[4];
            sel_coeffs((cob + r) % 3, cnm, cdn, nm, dn);
            float bv = bias2s[cob + r];
#pragma unroll
            for (int nf = 0; nf < 7; ++nf) {
                if (VAL[nf])
                    outp[OB[nf] + (cob + r) * 784] = rational_eval(acc[m][nf][r] + bv, nm, dn);
            }
        }
    }
}

// ---------------- launcher ----------------
extern "C" void kernel_launch(void* const* d_in, const int* in_sizes, int n_in,
                              void* d_out, int out_size, void* d_ws, size_t ws_size,
                              hipStream_t stream)
{
    const float* x      = (const float*)d_in[0];
    const float* w1     = (const float*)d_in[1];
    const float* gamma1 = (const float*)d_in[2];
    const float* beta1  = (const float*)d_in[3];
    const float* mean1  = (const float*)d_in[4];
    const float* var1   = (const float*)d_in[5];
    const float* num_r  = (const float*)d_in[6];
    const float* den_r  = (const float*)d_in[7];
    const float* num_g  = (const float*)d_in[8];
    const float* den_g  = (const float*)d_in[9];
    const float* num_b  = (const float*)d_in[10];
    const float* den_b  = (const float*)d_in[11];
    const float* w2     = (const float*)d_in[12];
    const float* gamma2 = (const float*)d_in[13];
    const float* beta2  = (const float*)d_in[14];
    const float* mean2  = (const float*)d_in[15];
    const float* var2   = (const float*)d_in[16];
    const float* wsc    = (const float*)d_in[17];
    const float* gammas = (const float*)d_in[18];
    const float* betas  = (const float*)d_in[19];
    const float* means  = (const float*)d_in[20];
    const float* vars_  = (const float*)d_in[21];

    char* base = (char*)d_ws;
    short* w1b  = (short*)(base + W1B_OFF);
    short* w2b  = (short*)(base + W2B_OFF);
    short* wsb  = (short*)(base + WSB_OFF);
    float* cs   = (float*)(base + CS_OFF);
    short* xt   = (short*)(base + XT_OFF);
    short* act  = (short*)(base + ACT_OFF);
    float* outp = (float*)d_out;

    float* bias1  = cs + 576;
    float* bias2s = cs + 768;
    const short* zbuf = wsb + 96;   // row 0's zero-padded channels (64 B of zeros)

    prep_all_kernel<<<7609, 256, 0, stream>>>(w1, w2, wsc,
                                              gamma1, beta1, mean1, var1,
                                              gamma2, beta2, mean2, var2,
                                              gammas, betas, means, vars_,
                                              w1b, w2b, wsb, cs, act);

    xpose_kernel<<<64 * 56, 256, 0, stream>>>(x, xt);

    convA_kernel<<<NBLK_A, 512, 0, stream>>>(xt, w1b, zbuf, bias1,
                                             num_r, den_r, num_g, den_g, num_b, den_b,
                                             act);

    convB_kernel<<<NBLK_B, 512, 0, stream>>>(act, xt, w2b, wsb, bias2s,
                                             num_r, den_r, num_g, den_g, num_b, den_b,
                                             outp);
}

// Round 14
// 130.715 us; speedup vs baseline: 1.1813x; 1.0693x over previous
//
#include <hip/hip_runtime.h>

#define EPSBN  1e-5f
#define NBLK_A 392           // convA: 50176 px / 128 per block; 392 = 8*49
#define NBLK_B 392           // convB: streaming, 128 px per block
#define PSTR   196

// ---------------- ws layout (bytes), total 61,701,888 (proven fit) ----------------
#define W1B_OFF 0u           // bf16 [192][9][96]   -> 331776
#define W2B_OFF 331776u      // bf16 [192][9][192]  -> 663552
#define WSB_OFF 995328u      // bf16 [192][128]     -> 49152 (ch 96..127 zero; row0 pad doubles as zbuf)
#define CS_OFF  1044480u     // 960 f32 -> 3840
#define XT_OFF  1048320u     // bf16 [64][56][56][96] -> 38535168 (unpadded NHWC)
#define ACT_OFF 39583488u    // bf16 [64][30][30][192] -> 22118400 (padded NHWC)

typedef __attribute__((ext_vector_type(8))) short bf16x8;
typedef __attribute__((ext_vector_type(4))) short bf16x4;
typedef __attribute__((ext_vector_type(4))) float f32x4;

#define WAITV(N) asm volatile("s_waitcnt vmcnt(" #N ")" ::: "memory")

__device__ __forceinline__ short f2bf(float f) {
    unsigned u = __float_as_uint(f);
    u += 0x7fffu + ((u >> 16) & 1u);
    return (short)(u >> 16);
}

__device__ __forceinline__ void gload16(const short* g, short* l) {
    __builtin_amdgcn_global_load_lds(
        (const __attribute__((address_space(1))) void*)g,
        (__attribute__((address_space(3))) void*)l, 16, 0, 0);
}

__device__ __forceinline__ float rational_eval(float v, const float* nm, const float* dn) {
    float p = nm[5];
    p = p * v + nm[4];
    p = p * v + nm[3];
    p = p * v + nm[2];
    p = p * v + nm[1];
    p = p * v + nm[0];
    float xa = fabsf(v);
    float q = 1.0f;
    float pw = xa;
    q += dn[0] * pw; pw *= xa;
    q += dn[1] * pw; pw *= xa;
    q += dn[2] * pw; pw *= xa;
    q += dn[3] * pw;
    float inv = __builtin_amdgcn_rcpf(q);
    inv = inv * (2.0f - q * inv);
    return p * inv;
}

__device__ __forceinline__ void sel_coeffs(int v, const float cnm[3][6], const float cdn[3][4],
                                           float nm[6], float dn[4]) {
#pragma unroll
    for (int i = 0; i < 6; i++) nm[i] = (v == 0) ? cnm[0][i] : ((v == 1) ? cnm[1][i] : cnm[2][i]);
#pragma unroll
    for (int i = 0; i < 4; i++) dn[i] = (v == 0) ? cdn[0][i] : ((v == 1) ? cdn[1][i] : cdn[2][i]);
}

// ---------------- fused prep: w1/w2/ws bf16-repack (scale inline), act ring-zero (8B), biases --------
// block ranges: [0,1296) w2 | [1296,1944) w1 | [1944,2040) ws | [2040,3432) ring | [3432] biases
extern "C" __global__ void prep_all_kernel(
    const float* __restrict__ w1, const float* __restrict__ w2, const float* __restrict__ wsc,
    const float* g1, const float* b1, const float* m1, const float* v1,
    const float* g2, const float* b2, const float* m2, const float* v2,
    const float* gs, const float* bs, const float* ms, const float* vs,
    short* __restrict__ w1b, short* __restrict__ w2b, short* __restrict__ wsb,
    float* __restrict__ cs, short* __restrict__ act)
{
    int blk = blockIdx.x;
    if (blk < 1296) {                               // w2 -> [co][kpos][192]
        int i = blk * 256 + threadIdx.x;
        int co = i / 1728;
        int r  = i - co * 1728;
        int kpos = r / 192;
        int ci = r - kpos * 192;
        float a = g2[co] * rsqrtf(v2[co] + EPSBN);
        w2b[i] = f2bf(w2[(co * 192 + ci) * 9 + kpos] * a);
    } else if (blk < 1944) {                        // w1 -> [co][kpos][96]
        int i = (blk - 1296) * 256 + threadIdx.x;
        int co = i / 864;
        int r  = i - co * 864;
        int kpos = r / 96;
        int ci = r - kpos * 96;
        float a = g1[co] * rsqrtf(v1[co] + EPSBN);
        w1b[i] = f2bf(w1[(co * 96 + ci) * 9 + kpos] * a);
    } else if (blk < 2040) {                        // ws -> [co][128], ci>=96 zero
        int i = (blk - 1944) * 256 + threadIdx.x;
        int co = i >> 7;
        int ci = i & 127;
        float a = gs[co] * rsqrtf(vs[co] + EPSBN);
        wsb[i] = (ci < 96) ? f2bf(wsc[co * 96 + ci] * a) : (short)0;
    } else if (blk < 3432) {                        // act pad-ring zero, 4 ch (8 B) per thread
        int i = (blk - 2040) * 256 + threadIdx.x;   // < 356352 exactly
        int c4 = i % 48;
        int t = i / 48;
        int rp = t % 116;
        int n = t / 116;
        int h, w;
        if (rp < 30)      { h = 0;  w = rp; }
        else if (rp < 60) { h = 29; w = rp - 30; }
        else { int k = rp - 60; h = (k >> 1) + 1; w = (k & 1) ? 29 : 0; }
        *(bf16x4*)&act[((n * 30 + h) * 30 + w) * 192 + c4 * 4] = (bf16x4)(short)0;
    } else {                                        // biases
        int i = threadIdx.x;
        if (i < 192) {
            float a1 = g1[i] * rsqrtf(v1[i] + EPSBN);
            float a2 = g2[i] * rsqrtf(v2[i] + EPSBN);
            float a3 = gs[i] * rsqrtf(vs[i] + EPSBN);
            cs[576 + i] = b1[i] - m1[i] * a1;
            cs[768 + i] = (b2[i] - m2[i] * a2) + (bs[i] - ms[i] * a3);
        }
    }
}

// x NCHW f32 [64][96][56][56] -> xt NHWC bf16 [64][56][56][96]; 8B-vector output writes
extern "C" __global__ __launch_bounds__(256)
void xpose_kernel(const float* __restrict__ x, short* __restrict__ xt)
{
    __shared__ float t[96 * 57];
    int b = blockIdx.x;
    int n = b / 56, h = b - n * 56;
    const float* src = x + n * (96 * 3136) + h * 56;
    for (int i = threadIdx.x; i < 96 * 28; i += 256) {
        int c = i / 28, w2 = i - c * 28;
        float2 v = *(const float2*)&src[c * 3136 + w2 * 2];
        t[c * 57 + w2 * 2]     = v.x;
        t[c * 57 + w2 * 2 + 1] = v.y;
    }
    __syncthreads();
    unsigned* dst = (unsigned*)(xt + (n * 56 + h) * 56 * 96);
    for (int i = threadIdx.x; i < 56 * 24; i += 256) {
        int w = i / 24, cp2 = i - (i / 24) * 24;     // 4 channels per iter
        unsigned u0 = (unsigned short)f2bf(t[(4 * cp2 + 0) * 57 + w]);
        unsigned u1 = (unsigned short)f2bf(t[(4 * cp2 + 1) * 57 + w]);
        unsigned u2 = (unsigned short)f2bf(t[(4 * cp2 + 2) * 57 + w]);
        unsigned u3 = (unsigned short)f2bf(t[(4 * cp2 + 3) * 57 + w]);
        uint2 pk; pk.x = u0 | (u1 << 16); pk.y = u2 | (u3 << 16);
        *(uint2*)&dst[w * 48 + cp2 * 2] = pk;
    }
}

// ---------------- kernel A: conv1(3x3 s2)+BN1+rational -> act (NHWC bf16, padded) ----------------
// 192co x 128px, 8 waves, BK=32; 3-buffer + counted vmcnt + raw barrier, full unroll. (R13, passed)
extern "C" __global__ __launch_bounds__(512, 4)
void convA_kernel(const short* __restrict__ xt,
                  const short* __restrict__ w1b,
                  const short* __restrict__ zbuf,
                  const float* __restrict__ bias1,
                  const float* __restrict__ num_r, const float* __restrict__ den_r,
                  const float* __restrict__ num_g, const float* __restrict__ den_g,
                  const float* __restrict__ num_b, const float* __restrict__ den_b,
                  short* __restrict__ act)
{
    __shared__ short lA[3][192 * 32];
    __shared__ short lB[3][128 * 32];

    const int tid  = threadIdx.x;
    const int lane = tid & 63;
    const int wave = tid >> 6;
    const int wm = wave >> 1, wn = wave & 1;
    const int lbid = (blockIdx.x & 7) * 49 + (blockIdx.x >> 3);
    const int p0   = lbid * 128;

    const int sA = (((tid & 3) ^ ((tid >> 3) & 3))) * 8;
    const int r1 = tid >> 2;
    const int aw1a = r1 * 864 + sA;
    const int aw1b = (128 + r1) * 864 + sA;

    int xb0; bool top, left;
    {
        int p = p0 + r1;
        int n = p / 784; int pr = p - n * 784;
        int oh = pr / 28; int ow = pr - oh * 28;
        xb0 = ((n * 56 + 2 * oh) * 56 + 2 * ow) * 96 + sA;
        top = (oh == 0); left = (ow == 0);
    }

    const int l15 = lane & 15, ksl = lane >> 4;
    int ard[3], brd[4];
#pragma unroll
    for (int m = 0; m < 3; ++m) {
        int row = wm * 48 + m * 16 + l15;
        ard[m] = row * 32 + ((ksl ^ ((row >> 1) & 3)) << 3);
    }
#pragma unroll
    for (int n = 0; n < 4; ++n) {
        int row = wn * 64 + n * 16 + l15;
        brd[n] = row * 32 + ((ksl ^ ((row >> 1) & 3)) << 3);
    }

    auto stage = [&](int buf, int t) {
        int kpos = t / 3, cb = t - 3 * kpos;
        int kh = kpos / 3, kw = kpos - 3 * kh;
        gload16(&w1b[aw1a + t * 32], &lA[buf][wave * 512]);
        if (tid < 256) gload16(&w1b[aw1b + t * 32], &lA[buf][4096 + wave * 512]);
        int bko = ((kh - 1) * 56 + (kw - 1)) * 96 + cb * 32;
        const short* src = (((kh == 0) && top) || ((kw == 0) && left)) ? zbuf : &xt[xb0 + bko];
        gload16(src, &lB[buf][wave * 512]);
    };

    f32x4 acc[3][4];
#pragma unroll
    for (int m = 0; m < 3; m++)
#pragma unroll
        for (int n = 0; n < 4; n++) acc[m][n] = (f32x4){0.f, 0.f, 0.f, 0.f};

    stage(0, 0);
    stage(1, 1);
    WAITV(0);
    __builtin_amdgcn_s_barrier();

#pragma unroll
    for (int t = 0; t < 27; ++t) {
        const int cur = t % 3;
        if (t + 2 < 27) stage((t + 2) % 3, t + 2);
        bf16x8 af[3];
#pragma unroll
        for (int m = 0; m < 3; ++m) af[m] = *(const bf16x8*)&lA[cur][ard[m]];
#pragma unroll
        for (int n = 0; n < 4; ++n) {
            bf16x8 bv = *(const bf16x8*)&lB[cur][brd[n]];
#pragma unroll
            for (int m = 0; m < 3; ++m)
                acc[m][n] = __builtin_amdgcn_mfma_f32_16x16x32_bf16(af[m], bv, acc[m][n], 0, 0, 0);
        }
        if (t + 1 < 27) {
            if (t + 2 < 27) {
                if (wave < 4) { WAITV(3); } else { WAITV(2); }
            } else {
                WAITV(0);
            }
            __builtin_amdgcn_s_barrier();
        }
    }

    float cnm[3][6], cdn[3][4];
#pragma unroll
    for (int i = 0; i < 6; i++) { cnm[0][i] = num_r[i]; cnm[1][i] = num_g[i]; cnm[2][i] = num_b[i]; }
#pragma unroll
    for (int i = 0; i < 4; i++) { cdn[0][i] = fabsf(den_r[i]); cdn[1][i] = fabsf(den_g[i]); cdn[2][i] = fabsf(den_b[i]); }

    int abase[4];
#pragma unroll
    for (int n = 0; n < 4; ++n) {
        int pp = p0 + wn * 64 + n * 16 + l15;
        int n2 = pp / 784; int r2 = pp - n2 * 784;
        int oh2 = r2 / 28; int ow2 = r2 - oh2 * 28;
        abase[n] = ((n2 * 30 + oh2 + 1) * 30 + ow2 + 1) * 192;
    }
#pragma unroll
    for (int m = 0; m < 3; ++m) {
        int cob = wm * 48 + m * 16 + (ksl << 2);
        float res[4][4];
#pragma unroll
        for (int r = 0; r < 4; ++r) {
            float nm[6], dn[4];
            sel_coeffs((cob + r) % 3, cnm, cdn, nm, dn);
            float bv = bias1[cob + r];
#pragma unroll
            for (int n = 0; n < 4; ++n)
                res[n][r] = rational_eval(acc[m][n][r] + bv, nm, dn);
        }
#pragma unroll
        for (int n = 0; n < 4; ++n) {
            bf16x4 pk;
#pragma unroll
            for (int r = 0; r < 4; ++r) pk[r] = f2bf(res[n][r]);
            *(bf16x4*)&act[abase[n] + cob] = pk;
        }
    }
}

// ---------------- kernel B (streaming, R9 verbatim): shortcut(1x1 s2, padded K=128)
// + conv2(3x3 s1, K=1728) into one acc; fused bias + rational -> out (NCHW f32).
// Block 192co x 128px, BK=64, 80 KB LDS (2 blocks/CU). ----------------
extern "C" __global__ __launch_bounds__(512, 4)
void convB_kernel(const short* __restrict__ act,
                  const short* __restrict__ xt,
                  const short* __restrict__ w2b,
                  const short* __restrict__ wsb,
                  const float* __restrict__ bias2s,
                  const float* __restrict__ num_r, const float* __restrict__ den_r,
                  const float* __restrict__ num_g, const float* __restrict__ den_g,
                  const float* __restrict__ num_b, const float* __restrict__ den_b,
                  float* __restrict__ outp)
{
    __shared__ short lA[2][192 * 64];   // 24 KB each
    __shared__ short lB[2][128 * 64];   // 16 KB each -> 80 KB total

    const int tid  = threadIdx.x;
    const int lane = tid & 63;
    const int wave = tid >> 6;
    const int wm = wave >> 1, wn = wave & 1;
    const int lbid = (blockIdx.x & 7) * 49 + (blockIdx.x >> 3);
    const int p0   = lbid * 128;

    const int s8 = (((tid & 7) ^ ((tid >> 3) & 7))) * 8;
    const int rA = tid >> 3;    // 0..63

    int awW[3], awS[3];
#pragma unroll
    for (int c = 0; c < 3; ++c) {
        int row = c * 64 + rA;
        awW[c] = row * 1728 + s8;
        awS[c] = row * 128 + s8;
    }
    int abB[2], xcB[2];
#pragma unroll
    for (int c = 0; c < 2; ++c) {
        int p = p0 + c * 64 + rA;
        int n = p / 784; int pr = p - n * 784;
        int oh = pr / 28; int ow = pr - oh * 28;
        abB[c] = ((n * 30 + oh) * 30 + ow) * 192 + s8;
        xcB[c] = ((n * 56 + 2 * oh) * 56 + 2 * ow) * 96 + s8;
    }

    const int l15 = lane & 15, ksl = lane >> 4;
    int ard[2][3], brd[2][4];
#pragma unroll
    for (int kk = 0; kk < 2; ++kk) {
#pragma unroll
        for (int m = 0; m < 3; ++m) {
            int row = wm * 48 + m * 16 + l15;
            ard[kk][m] = row * 64 + ((((kk << 2) | ksl) ^ (row & 7)) << 3);
        }
#pragma unroll
        for (int n = 0; n < 4; ++n) {
            int row = wn * 64 + n * 16 + l15;
            brd[kk][n] = row * 64 + ((((kk << 2) | ksl) ^ (row & 7)) << 3);
        }
    }

    // t 0..1: shortcut (wsb padded to 128 ch); t 2..28: conv2 (9 taps x 3 cb64)
    auto stage = [&](int buf, int t) {
        if (t < 2) {
#pragma unroll
            for (int c = 0; c < 3; ++c)
                gload16(&wsb[awS[c] + t * 64], &lA[buf][c * 4096 + wave * 512]);
#pragma unroll
            for (int c = 0; c < 2; ++c)
                gload16(&xt[xcB[c] + t * 64], &lB[buf][c * 4096 + wave * 512]);
        } else {
            int u = t - 2;
            int kpos = u / 3, cb = u - 3 * kpos;
            int kh = kpos / 3, kw = kpos - 3 * kh;
            int bko = (kh * 30 + kw) * 192 + cb * 64;
#pragma unroll
            for (int c = 0; c < 3; ++c)
                gload16(&w2b[awW[c] + u * 64], &lA[buf][c * 4096 + wave * 512]);
#pragma unroll
            for (int c = 0; c < 2; ++c)
                gload16(&act[abB[c] + bko], &lB[buf][c * 4096 + wave * 512]);
        }
    };

    f32x4 acc[3][4];
#pragma unroll
    for (int m = 0; m < 3; m++)
#pragma unroll
        for (int n = 0; n < 4; n++) acc[m][n] = (f32x4){0.f, 0.f, 0.f, 0.f};

    stage(0, 0);
    int cur = 0;
    for (int t = 0; t < 29; ++t) {
        __syncthreads();
        if (t + 1 < 29) stage(cur ^ 1, t + 1);
#pragma unroll
        for (int kk = 0; kk < 2; ++kk) {
            bf16x8 af[3];
#pragma unroll
            for (int m = 0; m < 3; ++m) af[m] = *(const bf16x8*)&lA[cur][ard[kk][m]];
#pragma unroll
            for (int n = 0; n < 4; ++n) {
                bf16x8 bv = *(const bf16x8*)&lB[cur][brd[kk][n]];
#pragma unroll
                for (int m = 0; m < 3; ++m)
                    acc[m][n] = __builtin_amdgcn_mfma_f32_16x16x32_bf16(af[m], bv, acc[m][n], 0, 0, 0);
            }
        }
        cur ^= 1;
    }

    float cnm[3][6], cdn[3][4];
#pragma unroll
    for (int i = 0; i < 6; i++) { cnm[0][i] = num_r[i]; cnm[1][i] = num_g[i]; cnm[2][i] = num_b[i]; }
#pragma unroll
    for (int i = 0; i < 4; i++) { cdn[0][i] = fabsf(den_r[i]); cdn[1][i] = fabsf(den_g[i]); cdn[2][i] = fabsf(den_b[i]); }

    int obase[4];
#pragma unroll
    for (int n = 0; n < 4; ++n) {
        int pp = p0 + wn * 64 + n * 16 + l15;
        int n2 = pp / 784; int r2 = pp - n2 * 784;
        int oh2 = r2 / 28; int ow2 = r2 - oh2 * 28;
        obase[n] = n2 * (192 * 784) + oh2 * 28 + ow2;
    }
#pragma unroll
    for (int m = 0; m < 3; ++m) {
        int cob = wm * 48 + m * 16 + (ksl << 2);
#pragma unroll
        for (int r = 0; r < 4; ++r) {
            float nm[6], dn[4];
            sel_coeffs((cob + r) % 3, cnm, cdn, nm, dn);
            float bv = bias2s[cob + r];
#pragma unroll
            for (int n = 0; n < 4; ++n) {
                int idx = obase[n] + (cob + r) * 784;
                outp[idx] = rational_eval(acc[m][n][r] + bv, nm, dn);
            }
        }
    }
}

// ---------------- launcher ----------------
extern "C" void kernel_launch(void* const* d_in, const int* in_sizes, int n_in,
                              void* d_out, int out_size, void* d_ws, size_t ws_size,
                              hipStream_t stream)
{
    const float* x      = (const float*)d_in[0];
    const float* w1     = (const float*)d_in[1];
    const float* gamma1 = (const float*)d_in[2];
    const float* beta1  = (const float*)d_in[3];
    const float* mean1  = (const float*)d_in[4];
    const float* var1   = (const float*)d_in[5];
    const float* num_r  = (const float*)d_in[6];
    const float* den_r  = (const float*)d_in[7];
    const float* num_g  = (const float*)d_in[8];
    const float* den_g  = (const float*)d_in[9];
    const float* num_b  = (const float*)d_in[10];
    const float* den_b  = (const float*)d_in[11];
    const float* w2     = (const float*)d_in[12];
    const float* gamma2 = (const float*)d_in[13];
    const float* beta2  = (const float*)d_in[14];
    const float* mean2  = (const float*)d_in[15];
    const float* var2   = (const float*)d_in[16];
    const float* wsc    = (const float*)d_in[17];
    const float* gammas = (const float*)d_in[18];
    const float* betas  = (const float*)d_in[19];
    const float* means  = (const float*)d_in[20];
    const float* vars_  = (const float*)d_in[21];

    char* base = (char*)d_ws;
    short* w1b  = (short*)(base + W1B_OFF);
    short* w2b  = (short*)(base + W2B_OFF);
    short* wsb  = (short*)(base + WSB_OFF);
    float* cs   = (float*)(base + CS_OFF);
    short* xt   = (short*)(base + XT_OFF);
    short* act  = (short*)(base + ACT_OFF);
    float* outp = (float*)d_out;

    float* bias1  = cs + 576;
    float* bias2s = cs + 768;
    const short* zbuf = wsb + 96;   // row 0's zero-padded channels (64 B of zeros)

    prep_all_kernel<<<3433, 256, 0, stream>>>(w1, w2, wsc,
                                              gamma1, beta1, mean1, var1,
                                              gamma2, beta2, mean2, var2,
                                              gammas, betas, means, vars_,
                                              w1b, w2b, wsb, cs, act);

    xpose_kernel<<<64 * 56, 256, 0, stream>>>(x, xt);

    convA_kernel<<<NBLK_A, 512, 0, stream>>>(xt, w1b, zbuf, bias1,
                                             num_r, den_r, num_g, den_g, num_b, den_b,
                                             act);

    convB_kernel<<<NBLK_B, 512, 0, stream>>>(act, xt, w2b, wsb, bias2s,
                                             num_r, den_r, num_g, den_g, num_b, den_b,
                                             outp);
}

// Round 15
// 127.118 us; speedup vs baseline: 1.2148x; 1.0283x over previous
//
#include <hip/hip_runtime.h>

#define EPSBN  1e-5f
#define NBLK_A 392           // convA: 50176 px / 128 per block; 392 = 8*49
#define NBLK_B 392           // convB: streaming, 128 px per block

// ---------------- ws layout (bytes), total 61,701,888 (proven fit) ----------------
#define W1B_OFF 0u           // bf16 [192][9][96]   -> 331776
#define W2B_OFF 331776u      // bf16 [192][9][192]  -> 663552
#define WSB_OFF 995328u      // bf16 [192][128]     -> 49152 (ch 96..127 zero; row0 pad doubles as zbuf)
#define CS_OFF  1044480u     // 960 f32 -> 3840
#define XT_OFF  1048320u     // bf16 [64][56][56][96] -> 38535168 (unpadded NHWC)
#define ACT_OFF 39583488u    // bf16 [64][30][30][192] -> 22118400 (padded NHWC)

typedef __attribute__((ext_vector_type(8))) short bf16x8;
typedef __attribute__((ext_vector_type(4))) short bf16x4;
typedef __attribute__((ext_vector_type(4))) float f32x4;

#define WAITV(N) asm volatile("s_waitcnt vmcnt(" #N ")" ::: "memory")

__device__ __forceinline__ short f2bf(float f) {
    unsigned u = __float_as_uint(f);
    u += 0x7fffu + ((u >> 16) & 1u);
    return (short)(u >> 16);
}

__device__ __forceinline__ void gload16(const short* g, short* l) {
    __builtin_amdgcn_global_load_lds(
        (const __attribute__((address_space(1))) void*)g,
        (__attribute__((address_space(3))) void*)l, 16, 0, 0);
}

__device__ __forceinline__ float rational_eval(float v, const float* nm, const float* dn) {
    float p = nm[5];
    p = p * v + nm[4];
    p = p * v + nm[3];
    p = p * v + nm[2];
    p = p * v + nm[1];
    p = p * v + nm[0];
    float xa = fabsf(v);
    float q = 1.0f;
    float pw = xa;
    q += dn[0] * pw; pw *= xa;
    q += dn[1] * pw; pw *= xa;
    q += dn[2] * pw; pw *= xa;
    q += dn[3] * pw;
    float inv = __builtin_amdgcn_rcpf(q);
    inv = inv * (2.0f - q * inv);
    return p * inv;
}

__device__ __forceinline__ void sel_coeffs(int v, const float cnm[3][6], const float cdn[3][4],
                                           float nm[6], float dn[4]) {
#pragma unroll
    for (int i = 0; i < 6; i++) nm[i] = (v == 0) ? cnm[0][i] : ((v == 1) ? cnm[1][i] : cnm[2][i]);
#pragma unroll
    for (int i = 0; i < 4; i++) dn[i] = (v == 0) ? cdn[0][i] : ((v == 1) ? cdn[1][i] : cdn[2][i]);
}

// ---------------- fused prep + xpose (single launch) ----------------
// block ranges: [0,1296) w2 | [1296,1944) w1 | [1944,2040) ws | [2040,3432) ring |
//               [3432,7016) xpose (64*56 rows) | [7016] biases
extern "C" __global__ __launch_bounds__(256)
void prep_all_kernel(
    const float* __restrict__ x,
    const float* __restrict__ w1, const float* __restrict__ w2, const float* __restrict__ wsc,
    const float* g1, const float* b1, const float* m1, const float* v1,
    const float* g2, const float* b2, const float* m2, const float* v2,
    const float* gs, const float* bs, const float* ms, const float* vs,
    short* __restrict__ w1b, short* __restrict__ w2b, short* __restrict__ wsb,
    float* __restrict__ cs, short* __restrict__ act, short* __restrict__ xt)
{
    __shared__ float t[96 * 57];
    int blk = blockIdx.x;
    if (blk < 1296) {                               // w2 -> [co][kpos][192]
        int i = blk * 256 + threadIdx.x;
        int co = i / 1728;
        int r  = i - co * 1728;
        int kpos = r / 192;
        int ci = r - kpos * 192;
        float a = g2[co] * rsqrtf(v2[co] + EPSBN);
        w2b[i] = f2bf(w2[(co * 192 + ci) * 9 + kpos] * a);
    } else if (blk < 1944) {                        // w1 -> [co][kpos][96]
        int i = (blk - 1296) * 256 + threadIdx.x;
        int co = i / 864;
        int r  = i - co * 864;
        int kpos = r / 96;
        int ci = r - kpos * 96;
        float a = g1[co] * rsqrtf(v1[co] + EPSBN);
        w1b[i] = f2bf(w1[(co * 96 + ci) * 9 + kpos] * a);
    } else if (blk < 2040) {                        // ws -> [co][128], ci>=96 zero
        int i = (blk - 1944) * 256 + threadIdx.x;
        int co = i >> 7;
        int ci = i & 127;
        float a = gs[co] * rsqrtf(vs[co] + EPSBN);
        wsb[i] = (ci < 96) ? f2bf(wsc[co * 96 + ci] * a) : (short)0;
    } else if (blk < 3432) {                        // act pad-ring zero, 4 ch (8 B) per thread
        int i = (blk - 2040) * 256 + threadIdx.x;   // < 356352 exactly
        int c4 = i % 48;
        int tt = i / 48;
        int rp = tt % 116;
        int n = tt / 116;
        int h, w;
        if (rp < 30)      { h = 0;  w = rp; }
        else if (rp < 60) { h = 29; w = rp - 30; }
        else { int k = rp - 60; h = (k >> 1) + 1; w = (k & 1) ? 29 : 0; }
        *(bf16x4*)&act[((n * 30 + h) * 30 + w) * 192 + c4 * 4] = (bf16x4)(short)0;
    } else if (blk < 7016) {                        // xpose: one (n,h) row per block
        int b = blk - 3432;
        int n = b / 56, h = b - n * 56;
        const float* src = x + n * (96 * 3136) + h * 56;
        for (int i = threadIdx.x; i < 96 * 28; i += 256) {
            int c = i / 28, w2i = i - c * 28;
            float2 v = *(const float2*)&src[c * 3136 + w2i * 2];
            t[c * 57 + w2i * 2]     = v.x;
            t[c * 57 + w2i * 2 + 1] = v.y;
        }
        __syncthreads();
        unsigned* dst = (unsigned*)(xt + (n * 56 + h) * 56 * 96);
        for (int i = threadIdx.x; i < 56 * 24; i += 256) {
            int w = i / 24, cp2 = i - (i / 24) * 24;
            unsigned u0 = (unsigned short)f2bf(t[(4 * cp2 + 0) * 57 + w]);
            unsigned u1 = (unsigned short)f2bf(t[(4 * cp2 + 1) * 57 + w]);
            unsigned u2 = (unsigned short)f2bf(t[(4 * cp2 + 2) * 57 + w]);
            unsigned u3 = (unsigned short)f2bf(t[(4 * cp2 + 3) * 57 + w]);
            uint2 pk; pk.x = u0 | (u1 << 16); pk.y = u2 | (u3 << 16);
            *(uint2*)&dst[w * 48 + cp2 * 2] = pk;
        }
    } else {                                        // biases
        int i = threadIdx.x;
        if (i < 192) {
            float a1 = g1[i] * rsqrtf(v1[i] + EPSBN);
            float a2 = g2[i] * rsqrtf(v2[i] + EPSBN);
            float a3 = gs[i] * rsqrtf(vs[i] + EPSBN);
            cs[576 + i] = b1[i] - m1[i] * a1;
            cs[768 + i] = (b2[i] - m2[i] * a2) + (bs[i] - ms[i] * a3);
        }
    }
}

// ---------------- kernel A: conv1(3x3 s2)+BN1+rational -> act (NHWC bf16, padded) ----------------
// 192co x 128px, 8 waves, BK=32; 3-buffer + counted vmcnt + raw barrier, full unroll.
extern "C" __global__ __launch_bounds__(512, 4)
void convA_kernel(const short* __restrict__ xt,
                  const short* __restrict__ w1b,
                  const short* __restrict__ zbuf,
                  const float* __restrict__ bias1,
                  const float* __restrict__ num_r, const float* __restrict__ den_r,
                  const float* __restrict__ num_g, const float* __restrict__ den_g,
                  const float* __restrict__ num_b, const float* __restrict__ den_b,
                  short* __restrict__ act)
{
    __shared__ short lA[3][192 * 32];
    __shared__ short lB[3][128 * 32];

    const int tid  = threadIdx.x;
    const int lane = tid & 63;
    const int wave = tid >> 6;
    const int wm = wave >> 1, wn = wave & 1;
    const int lbid = (blockIdx.x & 7) * 49 + (blockIdx.x >> 3);
    const int p0   = lbid * 128;

    const int sA = (((tid & 3) ^ ((tid >> 3) & 3))) * 8;
    const int r1 = tid >> 2;
    const int aw1a = r1 * 864 + sA;
    const int aw1b = (128 + r1) * 864 + sA;

    int xb0; bool top, left;
    {
        int p = p0 + r1;
        int n = p / 784; int pr = p - n * 784;
        int oh = pr / 28; int ow = pr - oh * 28;
        xb0 = ((n * 56 + 2 * oh) * 56 + 2 * ow) * 96 + sA;
        top = (oh == 0); left = (ow == 0);
    }

    const int l15 = lane & 15, ksl = lane >> 4;
    int ard[3], brd[4];
#pragma unroll
    for (int m = 0; m < 3; ++m) {
        int row = wm * 48 + m * 16 + l15;
        ard[m] = row * 32 + ((ksl ^ ((row >> 1) & 3)) << 3);
    }
#pragma unroll
    for (int n = 0; n < 4; ++n) {
        int row = wn * 64 + n * 16 + l15;
        brd[n] = row * 32 + ((ksl ^ ((row >> 1) & 3)) << 3);
    }

    auto stage = [&](int buf, int t) {
        int kpos = t / 3, cb = t - 3 * kpos;
        int kh = kpos / 3, kw = kpos - 3 * kh;
        gload16(&w1b[aw1a + t * 32], &lA[buf][wave * 512]);
        if (tid < 256) gload16(&w1b[aw1b + t * 32], &lA[buf][4096 + wave * 512]);
        int bko = ((kh - 1) * 56 + (kw - 1)) * 96 + cb * 32;
        const short* src = (((kh == 0) && top) || ((kw == 0) && left)) ? zbuf : &xt[xb0 + bko];
        gload16(src, &lB[buf][wave * 512]);
    };

    f32x4 acc[3][4];
#pragma unroll
    for (int m = 0; m < 3; m++)
#pragma unroll
        for (int n = 0; n < 4; n++) acc[m][n] = (f32x4){0.f, 0.f, 0.f, 0.f};

    stage(0, 0);
    stage(1, 1);
    WAITV(0);
    __builtin_amdgcn_s_barrier();

#pragma unroll
    for (int t = 0; t < 27; ++t) {
        const int cur = t % 3;
        if (t + 2 < 27) stage((t + 2) % 3, t + 2);
        bf16x8 af[3];
#pragma unroll
        for (int m = 0; m < 3; ++m) af[m] = *(const bf16x8*)&lA[cur][ard[m]];
        __builtin_amdgcn_s_setprio(1);
#pragma unroll
        for (int n = 0; n < 4; ++n) {
            bf16x8 bv = *(const bf16x8*)&lB[cur][brd[n]];
#pragma unroll
            for (int m = 0; m < 3; ++m)
                acc[m][n] = __builtin_amdgcn_mfma_f32_16x16x32_bf16(af[m], bv, acc[m][n], 0, 0, 0);
        }
        __builtin_amdgcn_s_setprio(0);
        if (t + 1 < 27) {
            if (t + 2 < 27) {
                if (wave < 4) { WAITV(3); } else { WAITV(2); }
            } else {
                WAITV(0);
            }
            __builtin_amdgcn_s_barrier();
        }
    }

    float cnm[3][6], cdn[3][4];
#pragma unroll
    for (int i = 0; i < 6; i++) { cnm[0][i] = num_r[i]; cnm[1][i] = num_g[i]; cnm[2][i] = num_b[i]; }
#pragma unroll
    for (int i = 0; i < 4; i++) { cdn[0][i] = fabsf(den_r[i]); cdn[1][i] = fabsf(den_g[i]); cdn[2][i] = fabsf(den_b[i]); }

    int abase[4];
#pragma unroll
    for (int n = 0; n < 4; ++n) {
        int pp = p0 + wn * 64 + n * 16 + l15;
        int n2 = pp / 784; int r2 = pp - n2 * 784;
        int oh2 = r2 / 28; int ow2 = r2 - oh2 * 28;
        abase[n] = ((n2 * 30 + oh2 + 1) * 30 + ow2 + 1) * 192;
    }
#pragma unroll
    for (int m = 0; m < 3; ++m) {
        int cob = wm * 48 + m * 16 + (ksl << 2);
        float res[4][4];
#pragma unroll
        for (int r = 0; r < 4; ++r) {
            float nm[6], dn[4];
            sel_coeffs((cob + r) % 3, cnm, cdn, nm, dn);
            float bv = bias1[cob + r];
#pragma unroll
            for (int n = 0; n < 4; ++n)
                res[n][r] = rational_eval(acc[m][n][r] + bv, nm, dn);
        }
#pragma unroll
        for (int n = 0; n < 4; ++n) {
            bf16x4 pk;
#pragma unroll
            for (int r = 0; r < 4; ++r) pk[r] = f2bf(res[n][r]);
            *(bf16x4*)&act[abase[n] + cob] = pk;
        }
    }
}

// ---------------- kernel B (streaming): shortcut(1x1 s2, padded K=128)
// + conv2(3x3 s1, K=1728) into one acc; fused bias + rational -> out (NCHW f32).
// Block 192co x 128px, BK=64, 80 KB LDS (2 blocks/CU). ----------------
extern "C" __global__ __launch_bounds__(512, 4)
void convB_kernel(const short* __restrict__ act,
                  const short* __restrict__ xt,
                  const short* __restrict__ w2b,
                  const short* __restrict__ wsb,
                  const float* __restrict__ bias2s,
                  const float* __restrict__ num_r, const float* __restrict__ den_r,
                  const float* __restrict__ num_g, const float* __restrict__ den_g,
                  const float* __restrict__ num_b, const float* __restrict__ den_b,
                  float* __restrict__ outp)
{
    __shared__ short lA[2][192 * 64];   // 24 KB each
    __shared__ short lB[2][128 * 64];   // 16 KB each -> 80 KB total

    const int tid  = threadIdx.x;
    const int lane = tid & 63;
    const int wave = tid >> 6;
    const int wm = wave >> 1, wn = wave & 1;
    const int lbid = (blockIdx.x & 7) * 49 + (blockIdx.x >> 3);
    const int p0   = lbid * 128;

    const int s8 = (((tid & 7) ^ ((tid >> 3) & 7))) * 8;
    const int rA = tid >> 3;    // 0..63

    int awW[3], awS[3];
#pragma unroll
    for (int c = 0; c < 3; ++c) {
        int row = c * 64 + rA;
        awW[c] = row * 1728 + s8;
        awS[c] = row * 128 + s8;
    }
    int abB[2], xcB[2];
#pragma unroll
    for (int c = 0; c < 2; ++c) {
        int p = p0 + c * 64 + rA;
        int n = p / 784; int pr = p - n * 784;
        int oh = pr / 28; int ow = pr - oh * 28;
        abB[c] = ((n * 30 + oh) * 30 + ow) * 192 + s8;
        xcB[c] = ((n * 56 + 2 * oh) * 56 + 2 * ow) * 96 + s8;
    }

    const int l15 = lane & 15, ksl = lane >> 4;
    int ard[2][3], brd[2][4];
#pragma unroll
    for (int kk = 0; kk < 2; ++kk) {
#pragma unroll
        for (int m = 0; m < 3; ++m) {
            int row = wm * 48 + m * 16 + l15;
            ard[kk][m] = row * 64 + ((((kk << 2) | ksl) ^ (row & 7)) << 3);
        }
#pragma unroll
        for (int n = 0; n < 4; ++n) {
            int row = wn * 64 + n * 16 + l15;
            brd[kk][n] = row * 64 + ((((kk << 2) | ksl) ^ (row & 7)) << 3);
        }
    }

    // t 0..1: shortcut (wsb padded to 128 ch); t 2..28: conv2 (9 taps x 3 cb64)
    auto stage = [&](int buf, int t) {
        if (t < 2) {
#pragma unroll
            for (int c = 0; c < 3; ++c)
                gload16(&wsb[awS[c] + t * 64], &lA[buf][c * 4096 + wave * 512]);
#pragma unroll
            for (int c = 0; c < 2; ++c)
                gload16(&xt[xcB[c] + t * 64], &lB[buf][c * 4096 + wave * 512]);
        } else {
            int u = t - 2;
            int kpos = u / 3, cb = u - 3 * kpos;
            int kh = kpos / 3, kw = kpos - 3 * kh;
            int bko = (kh * 30 + kw) * 192 + cb * 64;
#pragma unroll
            for (int c = 0; c < 3; ++c)
                gload16(&w2b[awW[c] + u * 64], &lA[buf][c * 4096 + wave * 512]);
#pragma unroll
            for (int c = 0; c < 2; ++c)
                gload16(&act[abB[c] + bko], &lB[buf][c * 4096 + wave * 512]);
        }
    };

    f32x4 acc[3][4];
#pragma unroll
    for (int m = 0; m < 3; m++)
#pragma unroll
        for (int n = 0; n < 4; n++) acc[m][n] = (f32x4){0.f, 0.f, 0.f, 0.f};

    stage(0, 0);
    int cur = 0;
    for (int t = 0; t < 29; ++t) {
        __syncthreads();
        if (t + 1 < 29) stage(cur ^ 1, t + 1);
        __builtin_amdgcn_s_setprio(1);
#pragma unroll
        for (int kk = 0; kk < 2; ++kk) {
            bf16x8 af[3];
#pragma unroll
            for (int m = 0; m < 3; ++m) af[m] = *(const bf16x8*)&lA[cur][ard[kk][m]];
#pragma unroll
            for (int n = 0; n < 4; ++n) {
                bf16x8 bv = *(const bf16x8*)&lB[cur][brd[kk][n]];
#pragma unroll
                for (int m = 0; m < 3; ++m)
                    acc[m][n] = __builtin_amdgcn_mfma_f32_16x16x32_bf16(af[m], bv, acc[m][n], 0, 0, 0);
            }
        }
        __builtin_amdgcn_s_setprio(0);
        cur ^= 1;
    }

    float cnm[3][6], cdn[3][4];
#pragma unroll
    for (int i = 0; i < 6; i++) { cnm[0][i] = num_r[i]; cnm[1][i] = num_g[i]; cnm[2][i] = num_b[i]; }
#pragma unroll
    for (int i = 0; i < 4; i++) { cdn[0][i] = fabsf(den_r[i]); cdn[1][i] = fabsf(den_g[i]); cdn[2][i] = fabsf(den_b[i]); }

    int obase[4];
#pragma unroll
    for (int n = 0; n < 4; ++n) {
        int pp = p0 + wn * 64 + n * 16 + l15;
        int n2 = pp / 784; int r2 = pp - n2 * 784;
        int oh2 = r2 / 28; int ow2 = r2 - oh2 * 28;
        obase[n] = n2 * (192 * 784) + oh2 * 28 + ow2;
    }
#pragma unroll
    for (int m = 0; m < 3; ++m) {
        int cob = wm * 48 + m * 16 + (ksl << 2);
#pragma unroll
        for (int r = 0; r < 4; ++r) {
            float nm[6], dn[4];
            sel_coeffs((cob + r) % 3, cnm, cdn, nm, dn);
            float bv = bias2s[cob + r];
#pragma unroll
            for (int n = 0; n < 4; ++n) {
                int idx = obase[n] + (cob + r) * 784;
                outp[idx] = rational_eval(acc[m][n][r] + bv, nm, dn);
            }
        }
    }
}

// ---------------- launcher ----------------
extern "C" void kernel_launch(void* const* d_in, const int* in_sizes, int n_in,
                              void* d_out, int out_size, void* d_ws, size_t ws_size,
                              hipStream_t stream)
{
    const float* x      = (const float*)d_in[0];
    const float* w1     = (const float*)d_in[1];
    const float* gamma1 = (const float*)d_in[2];
    const float* beta1  = (const float*)d_in[3];
    const float* mean1  = (const float*)d_in[4];
    const float* var1   = (const float*)d_in[5];
    const float* num_r  = (const float*)d_in[6];
    const float* den_r  = (const float*)d_in[7];
    const float* num_g  = (const float*)d_in[8];
    const float* den_g  = (const float*)d_in[9];
    const float* num_b  = (const float*)d_in[10];
    const float* den_b  = (const float*)d_in[11];
    const float* w2     = (const float*)d_in[12];
    const float* gamma2 = (const float*)d_in[13];
    const float* beta2  = (const float*)d_in[14];
    const float* mean2  = (const float*)d_in[15];
    const float* var2   = (const float*)d_in[16];
    const float* wsc    = (const float*)d_in[17];
    const float* gammas = (const float*)d_in[18];
    const float* betas  = (const float*)d_in[19];
    const float* means  = (const float*)d_in[20];
    const float* vars_  = (const float*)d_in[21];

    char* base = (char*)d_ws;
    short* w1b  = (short*)(base + W1B_OFF);
    short* w2b  = (short*)(base + W2B_OFF);
    short* wsb  = (short*)(base + WSB_OFF);
    float* cs   = (float*)(base + CS_OFF);
    short* xt   = (short*)(base + XT_OFF);
    short* act  = (short*)(base + ACT_OFF);
    float* outp = (float*)d_out;

    float* bias1  = cs + 576;
    float* bias2s = cs + 768;
    const short* zbuf = wsb + 96;   // row 0's zero-padded channels (64 B of zeros)

    prep_all_kernel<<<7017, 256, 0, stream>>>(x, w1, w2, wsc,
                                              gamma1, beta1, mean1, var1,
                                              gamma2, beta2, mean2, var2,
                                              gammas, betas, means, vars_,
                                              w1b, w2b, wsb, cs, act, xt);

    convA_kernel<<<NBLK_A, 512, 0, stream>>>(xt, w1b, zbuf, bias1,
                                             num_r, den_r, num_g, den_g, num_b, den_b,
                                             act);

    convB_kernel<<<NBLK_B, 512, 0, stream>>>(act, xt, w2b, wsb, bias2s,
                                             num_r, den_r, num_g, den_g, num_b, den_b,
                                             outp);
}

// Round 16
// 123.863 us; speedup vs baseline: 1.2467x; 1.0263x over previous
//
#include <hip/hip_runtime.h>

#define EPSBN  1e-5f
#define NBLK_A 392           // convA: 50176 px / 128 per block; 392 = 8*49
#define NBLK_B 392           // convB: streaming, 128 px per block

// ---------------- ws layout (bytes), total 61,701,888 (proven fit) ----------------
// w1t/w2t/wst are STAGING-ORDER tiled weights (read-swizzle baked into layout):
//   w2t[u][L], u<27, L<12288 : value = w2row(L>>6)[k = u*64 + ((((L>>3)&7)^((L>>6)&7))<<3) + (L&7)]
//   w1t[t][L], t<27, L<6144  : value = w1row(L>>5)[k = t*32 + ((((L>>3)&3)^(((L>>5)>>1)&3))<<3) + (L&7)]
//   wst[t][L], t<2,  L<12288 : same as w2t but k<128, k>=96 -> 0
#define W1B_OFF 0u           // bf16 27*6144  -> 331776
#define W2B_OFF 331776u      // bf16 27*12288 -> 663552
#define WSB_OFF 995328u      // bf16 2*12288  -> 49152
#define CS_OFF  1044480u     // 960 f32 -> 3840
#define XT_OFF  1048320u     // bf16 [64][56][56][96] -> 38535168 (unpadded NHWC)
#define ACT_OFF 39583488u    // bf16 [64][30][30][192] -> 22118400 (padded NHWC)

typedef __attribute__((ext_vector_type(8))) short bf16x8;
typedef __attribute__((ext_vector_type(4))) short bf16x4;
typedef __attribute__((ext_vector_type(4))) float f32x4;

#define WAITV(N) asm volatile("s_waitcnt vmcnt(" #N ")" ::: "memory")

__device__ __forceinline__ short f2bf(float f) {
    unsigned u = __float_as_uint(f);
    u += 0x7fffu + ((u >> 16) & 1u);
    return (short)(u >> 16);
}

__device__ __forceinline__ void gload16(const short* g, short* l) {
    __builtin_amdgcn_global_load_lds(
        (const __attribute__((address_space(1))) void*)g,
        (__attribute__((address_space(3))) void*)l, 16, 0, 0);
}

__device__ __forceinline__ float rational_eval(float v, const float* nm, const float* dn) {
    float p = nm[5];
    p = p * v + nm[4];
    p = p * v + nm[3];
    p = p * v + nm[2];
    p = p * v + nm[1];
    p = p * v + nm[0];
    float xa = fabsf(v);
    float q = 1.0f;
    float pw = xa;
    q += dn[0] * pw; pw *= xa;
    q += dn[1] * pw; pw *= xa;
    q += dn[2] * pw; pw *= xa;
    q += dn[3] * pw;
    float inv = __builtin_amdgcn_rcpf(q);
    inv = inv * (2.0f - q * inv);
    return p * inv;
}

__device__ __forceinline__ void sel_coeffs(int v, const float cnm[3][6], const float cdn[3][4],
                                           float nm[6], float dn[4]) {
#pragma unroll
    for (int i = 0; i < 6; i++) nm[i] = (v == 0) ? cnm[0][i] : ((v == 1) ? cnm[1][i] : cnm[2][i]);
#pragma unroll
    for (int i = 0; i < 4; i++) dn[i] = (v == 0) ? cdn[0][i] : ((v == 1) ? cdn[1][i] : cdn[2][i]);
}

// ---------------- fused prep + xpose (single launch) ----------------
// block ranges: [0,1296) w2t | [1296,1944) w1t | [1944,2040) wst | [2040,3432) ring |
//               [3432,7016) xpose (64*56 rows) | [7016] biases
extern "C" __global__ __launch_bounds__(256)
void prep_all_kernel(
    const float* __restrict__ x,
    const float* __restrict__ w1, const float* __restrict__ w2, const float* __restrict__ wsc,
    const float* g1, const float* b1, const float* m1, const float* v1,
    const float* g2, const float* b2, const float* m2, const float* v2,
    const float* gs, const float* bs, const float* ms, const float* vs,
    short* __restrict__ w1t, short* __restrict__ w2t, short* __restrict__ wst,
    float* __restrict__ cs, short* __restrict__ act, short* __restrict__ xt)
{
    __shared__ float t[96 * 57];
    int blk = blockIdx.x;
    if (blk < 1296) {                               // w2t: staging-order conv2 weights
        int i = blk * 256 + threadIdx.x;            // < 331776
        int u = i / 12288; int L = i - u * 12288;
        int row = L >> 6; int s = (L >> 3) & 7; int j = L & 7;
        int k = u * 64 + ((s ^ (row & 7)) << 3) + j;      // 0..1727
        int kpos = k / 192; int ci = k - kpos * 192;
        float a = g2[row] * rsqrtf(v2[row] + EPSBN);
        w2t[i] = f2bf(w2[(row * 192 + ci) * 9 + kpos] * a);
    } else if (blk < 1944) {                        // w1t: staging-order conv1 weights
        int i = (blk - 1296) * 256 + threadIdx.x;   // < 165888
        int u = i / 6144; int L = i - u * 6144;
        int row = L >> 5; int s = (L >> 3) & 3; int j = L & 7;
        int k = u * 32 + ((s ^ ((row >> 1) & 3)) << 3) + j;   // 0..863
        int kpos = k / 96; int ci = k - kpos * 96;
        float a = g1[row] * rsqrtf(v1[row] + EPSBN);
        w1t[i] = f2bf(w1[(row * 96 + ci) * 9 + kpos] * a);
    } else if (blk < 2040) {                        // wst: staging-order shortcut weights (K padded to 128)
        int i = (blk - 1944) * 256 + threadIdx.x;   // < 24576
        int u = i / 12288; int L = i - u * 12288;
        int row = L >> 6; int s = (L >> 3) & 7; int j = L & 7;
        int k = u * 64 + ((s ^ (row & 7)) << 3) + j;      // 0..127
        float a = gs[row] * rsqrtf(vs[row] + EPSBN);
        wst[i] = (k < 96) ? f2bf(wsc[row * 96 + k] * a) : (short)0;
    } else if (blk < 3432) {                        // act pad-ring zero, 4 ch (8 B) per thread
        int i = (blk - 2040) * 256 + threadIdx.x;   // < 356352
        int c4 = i % 48;
        int tt = i / 48;
        int rp = tt % 116;
        int n = tt / 116;
        int h, w;
        if (rp < 30)      { h = 0;  w = rp; }
        else if (rp < 60) { h = 29; w = rp - 30; }
        else { int k = rp - 60; h = (k >> 1) + 1; w = (k & 1) ? 29 : 0; }
        *(bf16x4*)&act[((n * 30 + h) * 30 + w) * 192 + c4 * 4] = (bf16x4)(short)0;
    } else if (blk < 7016) {                        // xpose: one (n,h) row per block
        int b = blk - 3432;
        int n = b / 56, h = b - n * 56;
        const float* src = x + n * (96 * 3136) + h * 56;
        for (int i = threadIdx.x; i < 96 * 28; i += 256) {
            int c = i / 28, w2i = i - c * 28;
            float2 v = *(const float2*)&src[c * 3136 + w2i * 2];
            t[c * 57 + w2i * 2]     = v.x;
            t[c * 57 + w2i * 2 + 1] = v.y;
        }
        __syncthreads();
        unsigned* dst = (unsigned*)(xt + (n * 56 + h) * 56 * 96);
        for (int i = threadIdx.x; i < 56 * 24; i += 256) {
            int w = i / 24, cp2 = i - (i / 24) * 24;
            unsigned u0 = (unsigned short)f2bf(t[(4 * cp2 + 0) * 57 + w]);
            unsigned u1 = (unsigned short)f2bf(t[(4 * cp2 + 1) * 57 + w]);
            unsigned u2 = (unsigned short)f2bf(t[(4 * cp2 + 2) * 57 + w]);
            unsigned u3 = (unsigned short)f2bf(t[(4 * cp2 + 3) * 57 + w]);
            uint2 pk; pk.x = u0 | (u1 << 16); pk.y = u2 | (u3 << 16);
            *(uint2*)&dst[w * 48 + cp2 * 2] = pk;
        }
    } else {                                        // biases
        int i = threadIdx.x;
        if (i < 192) {
            float a1 = g1[i] * rsqrtf(v1[i] + EPSBN);
            float a2 = g2[i] * rsqrtf(v2[i] + EPSBN);
            float a3 = gs[i] * rsqrtf(vs[i] + EPSBN);
            cs[576 + i] = b1[i] - m1[i] * a1;
            cs[768 + i] = (b2[i] - m2[i] * a2) + (bs[i] - ms[i] * a3);
        }
    }
}

// ---------------- kernel A: conv1(3x3 s2)+BN1+rational -> act (NHWC bf16, padded) ----------------
// 192co x 128px, 8 waves, BK=32; 3-buffer + counted vmcnt + raw barrier, full unroll.
// A-staging reads w1t linearly: 1 contiguous KB per wave-instr (1 segment).
extern "C" __global__ __launch_bounds__(512, 4)
void convA_kernel(const short* __restrict__ xt,
                  const short* __restrict__ w1t,
                  const short* __restrict__ zbuf,
                  const float* __restrict__ bias1,
                  const float* __restrict__ num_r, const float* __restrict__ den_r,
                  const float* __restrict__ num_g, const float* __restrict__ den_g,
                  const float* __restrict__ num_b, const float* __restrict__ den_b,
                  short* __restrict__ act)
{
    __shared__ short lA[3][192 * 32];
    __shared__ short lB[3][128 * 32];

    const int tid  = threadIdx.x;
    const int lane = tid & 63;
    const int wave = tid >> 6;
    const int wm = wave >> 1, wn = wave & 1;
    const int lbid = (blockIdx.x & 7) * 49 + (blockIdx.x >> 3);
    const int p0   = lbid * 128;

    const int sA = (((tid & 3) ^ ((tid >> 3) & 3))) * 8;   // xt B-path swizzle (unchanged)
    const int r1 = tid >> 2;

    int xb0; bool top, left;
    {
        int p = p0 + r1;
        int n = p / 784; int pr = p - n * 784;
        int oh = pr / 28; int ow = pr - oh * 28;
        xb0 = ((n * 56 + 2 * oh) * 56 + 2 * ow) * 96 + sA;
        top = (oh == 0); left = (ow == 0);
    }

    const int l15 = lane & 15, ksl = lane >> 4;
    int ard[3], brd[4];
#pragma unroll
    for (int m = 0; m < 3; ++m) {
        int row = wm * 48 + m * 16 + l15;
        ard[m] = row * 32 + ((ksl ^ ((row >> 1) & 3)) << 3);
    }
#pragma unroll
    for (int n = 0; n < 4; ++n) {
        int row = wn * 64 + n * 16 + l15;
        brd[n] = row * 32 + ((ksl ^ ((row >> 1) & 3)) << 3);
    }

    const int aoff = wave * 512 + lane * 8;     // linear staging offset (shorts)

    auto stage = [&](int buf, int t) {
        const short* aw = &w1t[t * 6144 + aoff];
        gload16(aw, &lA[buf][wave * 512]);
        if (tid < 256) gload16(aw + 4096, &lA[buf][4096 + wave * 512]);
        int kpos = t / 3, cb = t - 3 * kpos;
        int kh = kpos / 3, kw = kpos - 3 * kh;
        int bko = ((kh - 1) * 56 + (kw - 1)) * 96 + cb * 32;
        const short* src = (((kh == 0) && top) || ((kw == 0) && left)) ? zbuf : &xt[xb0 + bko];
        gload16(src, &lB[buf][wave * 512]);
    };

    f32x4 acc[3][4];
#pragma unroll
    for (int m = 0; m < 3; m++)
#pragma unroll
        for (int n = 0; n < 4; n++) acc[m][n] = (f32x4){0.f, 0.f, 0.f, 0.f};

    stage(0, 0);
    stage(1, 1);
    WAITV(0);
    __builtin_amdgcn_s_barrier();

#pragma unroll
    for (int t = 0; t < 27; ++t) {
        const int cur = t % 3;
        if (t + 2 < 27) stage((t + 2) % 3, t + 2);
        bf16x8 af[3];
#pragma unroll
        for (int m = 0; m < 3; ++m) af[m] = *(const bf16x8*)&lA[cur][ard[m]];
        __builtin_amdgcn_s_setprio(1);
#pragma unroll
        for (int n = 0; n < 4; ++n) {
            bf16x8 bv = *(const bf16x8*)&lB[cur][brd[n]];
#pragma unroll
            for (int m = 0; m < 3; ++m)
                acc[m][n] = __builtin_amdgcn_mfma_f32_16x16x32_bf16(af[m], bv, acc[m][n], 0, 0, 0);
        }
        __builtin_amdgcn_s_setprio(0);
        if (t + 1 < 27) {
            if (t + 2 < 27) {
                if (wave < 4) { WAITV(3); } else { WAITV(2); }
            } else {
                WAITV(0);
            }
            __builtin_amdgcn_s_barrier();
        }
    }

    float cnm[3][6], cdn[3][4];
#pragma unroll
    for (int i = 0; i < 6; i++) { cnm[0][i] = num_r[i]; cnm[1][i] = num_g[i]; cnm[2][i] = num_b[i]; }
#pragma unroll
    for (int i = 0; i < 4; i++) { cdn[0][i] = fabsf(den_r[i]); cdn[1][i] = fabsf(den_g[i]); cdn[2][i] = fabsf(den_b[i]); }

    int abase[4];
#pragma unroll
    for (int n = 0; n < 4; ++n) {
        int pp = p0 + wn * 64 + n * 16 + l15;
        int n2 = pp / 784; int r2 = pp - n2 * 784;
        int oh2 = r2 / 28; int ow2 = r2 - oh2 * 28;
        abase[n] = ((n2 * 30 + oh2 + 1) * 30 + ow2 + 1) * 192;
    }
#pragma unroll
    for (int m = 0; m < 3; ++m) {
        int cob = wm * 48 + m * 16 + (ksl << 2);
        float res[4][4];
#pragma unroll
        for (int r = 0; r < 4; ++r) {
            float nm[6], dn[4];
            sel_coeffs((cob + r) % 3, cnm, cdn, nm, dn);
            float bv = bias1[cob + r];
#pragma unroll
            for (int n = 0; n < 4; ++n)
                res[n][r] = rational_eval(acc[m][n][r] + bv, nm, dn);
        }
#pragma unroll
        for (int n = 0; n < 4; ++n) {
            bf16x4 pk;
#pragma unroll
            for (int r = 0; r < 4; ++r) pk[r] = f2bf(res[n][r]);
            *(bf16x4*)&act[abase[n] + cob] = pk;
        }
    }
}

// ---------------- kernel B (streaming): shortcut(1x1 s2, padded K=128)
// + conv2(3x3 s1, K=1728) into one acc; fused bias + rational -> out (NCHW f32).
// Block 192co x 128px, BK=64, 80 KB LDS (2 blocks/CU). A/sc staged from tiled
// weights: 1 contiguous KB per wave-instr (1 segment). ----------------
extern "C" __global__ __launch_bounds__(512, 4)
void convB_kernel(const short* __restrict__ act,
                  const short* __restrict__ xt,
                  const short* __restrict__ w2t,
                  const short* __restrict__ wst,
                  const float* __restrict__ bias2s,
                  const float* __restrict__ num_r, const float* __restrict__ den_r,
                  const float* __restrict__ num_g, const float* __restrict__ den_g,
                  const float* __restrict__ num_b, const float* __restrict__ den_b,
                  float* __restrict__ outp)
{
    __shared__ short lA[2][192 * 64];   // 24 KB each
    __shared__ short lB[2][128 * 64];   // 16 KB each -> 80 KB total

    const int tid  = threadIdx.x;
    const int lane = tid & 63;
    const int wave = tid >> 6;
    const int wm = wave >> 1, wn = wave & 1;
    const int lbid = (blockIdx.x & 7) * 49 + (blockIdx.x >> 3);
    const int p0   = lbid * 128;

    const int s8 = (((tid & 7) ^ ((tid >> 3) & 7))) * 8;   // act/xt B-path swizzle (unchanged)
    const int rA = tid >> 3;    // 0..63

    int abB[2], xcB[2];
#pragma unroll
    for (int c = 0; c < 2; ++c) {
        int p = p0 + c * 64 + rA;
        int n = p / 784; int pr = p - n * 784;
        int oh = pr / 28; int ow = pr - oh * 28;
        abB[c] = ((n * 30 + oh) * 30 + ow) * 192 + s8;
        xcB[c] = ((n * 56 + 2 * oh) * 56 + 2 * ow) * 96 + s8;
    }

    const int l15 = lane & 15, ksl = lane >> 4;
    int ard[2][3], brd[2][4];
#pragma unroll
    for (int kk = 0; kk < 2; ++kk) {
#pragma unroll
        for (int m = 0; m < 3; ++m) {
            int row = wm * 48 + m * 16 + l15;
            ard[kk][m] = row * 64 + ((((kk << 2) | ksl) ^ (row & 7)) << 3);
        }
#pragma unroll
        for (int n = 0; n < 4; ++n) {
            int row = wn * 64 + n * 16 + l15;
            brd[kk][n] = row * 64 + ((((kk << 2) | ksl) ^ (row & 7)) << 3);
        }
    }

    const int aoff = wave * 512 + lane * 8;     // linear staging offset (shorts)

    // t 0..1: shortcut (wst); t 2..28: conv2 (w2t)
    auto stage = [&](int buf, int t) {
        if (t < 2) {
            const short* aw = &wst[t * 12288 + aoff];
#pragma unroll
            for (int c = 0; c < 3; ++c)
                gload16(aw + c * 4096, &lA[buf][c * 4096 + wave * 512]);
#pragma unroll
            for (int c = 0; c < 2; ++c)
                gload16(&xt[xcB[c] + t * 64], &lB[buf][c * 4096 + wave * 512]);
        } else {
            int u = t - 2;
            const short* aw = &w2t[u * 12288 + aoff];
#pragma unroll
            for (int c = 0; c < 3; ++c)
                gload16(aw + c * 4096, &lA[buf][c * 4096 + wave * 512]);
            int kpos = u / 3, cb = u - 3 * kpos;
            int kh = kpos / 3, kw = kpos - 3 * kh;
            int bko = (kh * 30 + kw) * 192 + cb * 64;
#pragma unroll
            for (int c = 0; c < 2; ++c)
                gload16(&act[abB[c] + bko], &lB[buf][c * 4096 + wave * 512]);
        }
    };

    f32x4 acc[3][4];
#pragma unroll
    for (int m = 0; m < 3; m++)
#pragma unroll
        for (int n = 0; n < 4; n++) acc[m][n] = (f32x4){0.f, 0.f, 0.f, 0.f};

    stage(0, 0);
    int cur = 0;
    for (int t = 0; t < 29; ++t) {
        __syncthreads();
        if (t + 1 < 29) stage(cur ^ 1, t + 1);
        __builtin_amdgcn_s_setprio(1);
#pragma unroll
        for (int kk = 0; kk < 2; ++kk) {
            bf16x8 af[3];
#pragma unroll
            for (int m = 0; m < 3; ++m) af[m] = *(const bf16x8*)&lA[cur][ard[kk][m]];
#pragma unroll
            for (int n = 0; n < 4; ++n) {
                bf16x8 bv = *(const bf16x8*)&lB[cur][brd[kk][n]];
#pragma unroll
                for (int m = 0; m < 3; ++m)
                    acc[m][n] = __builtin_amdgcn_mfma_f32_16x16x32_bf16(af[m], bv, acc[m][n], 0, 0, 0);
            }
        }
        __builtin_amdgcn_s_setprio(0);
        cur ^= 1;
    }

    float cnm[3][6], cdn[3][4];
#pragma unroll
    for (int i = 0; i < 6; i++) { cnm[0][i] = num_r[i]; cnm[1][i] = num_g[i]; cnm[2][i] = num_b[i]; }
#pragma unroll
    for (int i = 0; i < 4; i++) { cdn[0][i] = fabsf(den_r[i]); cdn[1][i] = fabsf(den_g[i]); cdn[2][i] = fabsf(den_b[i]); }

    int obase[4];
#pragma unroll
    for (int n = 0; n < 4; ++n) {
        int pp = p0 + wn * 64 + n * 16 + l15;
        int n2 = pp / 784; int r2 = pp - n2 * 784;
        int oh2 = r2 / 28; int ow2 = r2 - oh2 * 28;
        obase[n] = n2 * (192 * 784) + oh2 * 28 + ow2;
    }
#pragma unroll
    for (int m = 0; m < 3; ++m) {
        int cob = wm * 48 + m * 16 + (ksl << 2);
#pragma unroll
        for (int r = 0; r < 4; ++r) {
            float nm[6], dn[4];
            sel_coeffs((cob + r) % 3, cnm, cdn, nm, dn);
            float bv = bias2s[cob + r];
#pragma unroll
            for (int n = 0; n < 4; ++n) {
                int idx = obase[n] + (cob + r) * 784;
                outp[idx] = rational_eval(acc[m][n][r] + bv, nm, dn);
            }
        }
    }
}

// ---------------- launcher ----------------
extern "C" void kernel_launch(void* const* d_in, const int* in_sizes, int n_in,
                              void* d_out, int out_size, void* d_ws, size_t ws_size,
                              hipStream_t stream)
{
    const float* x      = (const float*)d_in[0];
    const float* w1     = (const float*)d_in[1];
    const float* gamma1 = (const float*)d_in[2];
    const float* beta1  = (const float*)d_in[3];
    const float* mean1  = (const float*)d_in[4];
    const float* var1   = (const float*)d_in[5];
    const float* num_r  = (const float*)d_in[6];
    const float* den_r  = (const float*)d_in[7];
    const float* num_g  = (const float*)d_in[8];
    const float* den_g  = (const float*)d_in[9];
    const float* num_b  = (const float*)d_in[10];
    const float* den_b  = (const float*)d_in[11];
    const float* w2     = (const float*)d_in[12];
    const float* gamma2 = (const float*)d_in[13];
    const float* beta2  = (const float*)d_in[14];
    const float* mean2  = (const float*)d_in[15];
    const float* var2   = (const float*)d_in[16];
    const float* wsc    = (const float*)d_in[17];
    const float* gammas = (const float*)d_in[18];
    const float* betas  = (const float*)d_in[19];
    const float* means  = (const float*)d_in[20];
    const float* vars_  = (const float*)d_in[21];

    char* base = (char*)d_ws;
    short* w1t  = (short*)(base + W1B_OFF);
    short* w2t  = (short*)(base + W2B_OFF);
    short* wst  = (short*)(base + WSB_OFF);
    float* cs   = (float*)(base + CS_OFF);
    short* xt   = (short*)(base + XT_OFF);
    short* act  = (short*)(base + ACT_OFF);
    float* outp = (float*)d_out;

    float* bias1  = cs + 576;
    float* bias2s = cs + 768;
    // wst chunk u=1, L in [32,64): row 0, s>=4 -> k>=96 -> zeros by construction (64 B)
    const short* zbuf = wst + 12288 + 32;

    prep_all_kernel<<<7017, 256, 0, stream>>>(x, w1, w2, wsc,
                                              gamma1, beta1, mean1, var1,
                                              gamma2, beta2, mean2, var2,
                                              gammas, betas, means, vars_,
                                              w1t, w2t, wst, cs, act, xt);

    convA_kernel<<<NBLK_A, 512, 0, stream>>>(xt, w1t, zbuf, bias1,
                                             num_r, den_r, num_g, den_g, num_b, den_b,
                                             act);

    convB_kernel<<<NBLK_B, 512, 0, stream>>>(act, xt, w2t, wst, bias2s,
                                             num_r, den_r, num_g, den_g, num_b, den_b,
                                             outp);
}